// Round 2
// baseline (2407.512 us; speedup 1.0000x reference)
//
#include <hip/hip_runtime.h>

typedef unsigned int uint32;

#define B_SZ 4
#define T_SZ 4096
#define DMODEL 512
#define NHEAD 8
#define DH 64
#define NHASH 4
#define BH (B_SZ*NHEAD)      // 32
#define NBUCK 256            // global buckets per bh row (4 rounds * 64)
#define TOT (NHASH*T_SZ)     // 16384

// ---------------- K0: zero histogram ----------------
__global__ void k0_zero(int* hist){ hist[blockIdx.x*256 + threadIdx.x] = 0; }

// ---------------- K1: qk (f64) + v (f32) GEMMs, merged layout [bh][t][64] ----
__global__ __launch_bounds__(256) void k1_qkv(const float* __restrict__ qin,
    const float* __restrict__ Wqk, const float* __restrict__ Wv,
    float* __restrict__ qk32, float* __restrict__ v32, double* __restrict__ qk64)
{
  __shared__ float qs[8*512];
  int tid = threadIdx.x, blk = blockIdx.x;
  int tok0 = blk*8;
  const float4* src = (const float4*)(qin + (size_t)tok0*512);
  float4* qs4 = (float4*)qs;
  #pragma unroll
  for (int k=0;k<4;k++) qs4[tid + k*256] = src[tid + k*256];
  __syncthreads();
  double aq0[8], aq1[8]; float av0[8], av1[8];
  #pragma unroll
  for (int r=0;r<8;r++){ aq0[r]=0.0; aq1[r]=0.0; av0[r]=0.f; av1[r]=0.f; }
  const float2* wq2 = (const float2*)Wqk;
  const float2* wv2 = (const float2*)Wv;
  for (int d=0; d<512; d++){
    float2 wq = wq2[d*256 + tid];
    float2 wv = wv2[d*256 + tid];
    double dq0 = (double)wq.x, dq1 = (double)wq.y;
    #pragma unroll
    for (int r=0;r<8;r++){
      float x = qs[r*512+d];
      double xd = (double)x;
      aq0[r] += xd*dq0; aq1[r] += xd*dq1;
      av0[r] += x*wv.x; av1[r] += x*wv.y;
    }
  }
  int j0 = 2*tid;
  int head = j0 >> 6, dd = j0 & 63;
  #pragma unroll
  for (int r=0;r<8;r++){
    int tok = tok0 + r; int b = tok >> 12; int tp = tok & 4095;
    size_t idx = ((size_t)(b*NHEAD+head)*T_SZ + tp)*DH + dd;
    qk32[idx] = (float)aq0[r]; qk32[idx+1] = (float)aq1[r];
    v32[idx]  = av0[r];        v32[idx+1]  = av1[r];
    qk64[idx] = aq0[r];        qk64[idx+1] = aq1[r];
  }
}

// ---------------- K2: LSH hashing (f64) + histogram ----------------
__global__ __launch_bounds__(256) void k2_hash(const double* __restrict__ qk64,
    const float* __restrict__ rot, unsigned short* __restrict__ bucket, int* __restrict__ hist)
{
  int gid = blockIdx.x*256 + threadIdx.x;  // [0, BH*NHASH*T)
  int t = gid & (T_SZ-1);
  int h = (gid >> 12) & 3;
  int bh = gid >> 14;
  const double* row = qk64 + ((size_t)bh*T_SZ + t)*DH;
  double acc[32];
  #pragma unroll
  for (int i=0;i<32;i++) acc[i]=0.0;
  for (int dd=0; dd<64; dd++){
    double q = row[dd];
    const float* rp = rot + dd*(NHASH*32) + h*32;
    #pragma unroll
    for (int i=0;i<32;i++) acc[i] += q * (double)rp[i];
  }
  // argmax over [rotated, -rotated], first occurrence wins
  double best = acc[0]; int bk = 0;
  #pragma unroll
  for (int k=1;k<64;k++){
    double vv = (k<32)? acc[k] : -acc[k-32];
    if (vv > best){ best = vv; bk = k; }
  }
  int g = bk + (h<<6);
  bucket[((bh*NHASH + h)<<12) + t] = (unsigned short)g;
  atomicAdd(&hist[bh*NBUCK + g], 1);
}

// ---------------- K3: per-bh exclusive prefix over 256 buckets ----------------
__global__ __launch_bounds__(256) void k3_scan(const int* __restrict__ hist, int* __restrict__ starts){
  __shared__ int s[256];
  int bh = blockIdx.x, tid = threadIdx.x;
  int v = hist[bh*256 + tid];
  s[tid] = v; __syncthreads();
  for (int off=1; off<256; off<<=1){
    int a = (tid >= off) ? s[tid-off] : 0;
    __syncthreads();
    s[tid] += a;
    __syncthreads();
  }
  starts[bh*256 + tid] = s[tid] - v;  // exclusive
}

// ---------------- K3b: stable counting-sort scatter (one wave per (bh,bucket)) -
__global__ __launch_bounds__(64) void k3b_scatter(const unsigned short* __restrict__ bucket,
    const int* __restrict__ starts, int* __restrict__ st)
{
  int blk = blockIdx.x;
  int bh = blk >> 8; int g = blk & 255; int h = g >> 6;
  int lane = threadIdx.x;
  const unsigned short* brow = bucket + ((bh*NHASH + h)<<12);
  int base = starts[bh*NBUCK + g];
  for (int step=0; step<64; step++){
    int t = step*64 + lane;
    bool pred = (brow[t] == (unsigned short)g);
    unsigned long long mask = __ballot(pred);
    if (pred){
      int off = __popcll(mask & ((1ull<<lane) - 1ull));
      st[bh*TOT + base + off] = t;
    }
    base += __popcll(mask);
  }
}

// ---------------- K4: chunked LSH attention (one wave per (bh,chunk)) ---------
__global__ __launch_bounds__(64) void k4_attn(const float* __restrict__ qk32,
    const float* __restrict__ v32, const int* __restrict__ st,
    float* __restrict__ lse_out, _Float16* __restrict__ o_out)
{
  __shared__ float k_lds[128*64];
  __shared__ float v_lds[128*64];
  __shared__ int kv_t[128];
  int blk = blockIdx.x;
  int bh = blk >> 8; int c = blk & 255;
  int h = c >> 6; int cp = (c + 255) & 255;  // previous chunk, wraps over all 256
  int lane = threadIdx.x;
  const int* strow = st + bh*TOT;
  #pragma unroll
  for (int rr=0; rr<2; rr++){
    int j = lane + rr*64;
    int slot = rr ? (cp*64 + lane) : (c*64 + lane);
    int t = strow[slot];
    kv_t[j] = t;
    const float4* kr = (const float4*)(qk32 + ((size_t)bh*T_SZ + t)*DH);
    const float4* vr = (const float4*)(v32  + ((size_t)bh*T_SZ + t)*DH);
    float4 tmp[16];
    float ss = 0.f;
    #pragma unroll
    for (int q4=0;q4<16;q4++){
      float4 x = kr[q4]; tmp[q4] = x;
      ss += x.x*x.x + x.y*x.y + x.z*x.z + x.w*x.w;
    }
    float sc = 1.0f / fmaxf(sqrtf(ss), 1e-12f);
    float4* kd = (float4*)&k_lds[j*64];
    float4* vd = (float4*)&v_lds[j*64];
    #pragma unroll
    for (int q4=0;q4<16;q4++){
      float4 x = tmp[q4];
      x.x*=sc; x.y*=sc; x.z*=sc; x.w*=sc;
      kd[q4] = x;
      vd[q4] = vr[q4];
    }
  }
  __syncthreads();
  int tq = kv_t[lane];
  float qreg[64];
  const float4* qrow = (const float4*)(qk32 + ((size_t)bh*T_SZ + tq)*DH);
  #pragma unroll
  for (int q4=0;q4<16;q4++){
    float4 x = qrow[q4];
    qreg[4*q4]=x.x; qreg[4*q4+1]=x.y; qreg[4*q4+2]=x.z; qreg[4*q4+3]=x.w;
  }
  float m = -1e30f, l = 0.f;
  float o[64];
  #pragma unroll
  for (int d=0;d<64;d++) o[d]=0.f;
  for (int j=0;j<128;j++){
    const float4* kj = (const float4*)&k_lds[j*64];
    float s0=0.f, s1=0.f, s2=0.f, s3=0.f;   // 4-way ILP on the dot chain
    #pragma unroll
    for (int q4=0;q4<16;q4++){
      float4 kk = kj[q4];
      s0 += qreg[4*q4]  *kk.x; s1 += qreg[4*q4+1]*kk.y;
      s2 += qreg[4*q4+2]*kk.z; s3 += qreg[4*q4+3]*kk.w;
    }
    float s = ((s0+s1)+(s2+s3)) * 0.125f;
    if (kv_t[j] == tq) s = -50000.0f;
    if (s > m){
      float r = __expf(m - s);
      l *= r;
      #pragma unroll
      for (int d=0;d<64;d++) o[d]*=r;
      m = s;
    }
    float w = __expf(s - m);
    l += w;
    const float4* vj = (const float4*)&v_lds[j*64];
    #pragma unroll
    for (int q4=0;q4<16;q4++){
      float4 vv = vj[q4];
      o[4*q4]   += w*vv.x; o[4*q4+1] += w*vv.y;
      o[4*q4+2] += w*vv.z; o[4*q4+3] += w*vv.w;
    }
  }
  float invl = 1.0f / l;
  float lse = m + logf(l);
  size_t rowidx = (size_t)(bh*NHASH + h)*T_SZ + tq;
  lse_out[rowidx] = lse;
  uint32* orow = (uint32*)(o_out + rowidx*DH);
  #pragma unroll
  for (int d2=0; d2<32; d2++){
    union { _Float16 hh[2]; uint32 u; } p;
    p.hh[0] = (_Float16)(o[2*d2]*invl);
    p.hh[1] = (_Float16)(o[2*d2+1]*invl);
    orow[d2] = p.u;
  }
}

// ---------------- K5: combine hash rounds, unmerge heads ----------------
__global__ __launch_bounds__(256) void k5_comb(const float* __restrict__ lse,
    const _Float16* __restrict__ o_f16, float* __restrict__ X)
{
  int gid = blockIdx.x*256 + threadIdx.x;  // [0, BH*T)
  int t = gid & (T_SZ-1);
  int bh = gid >> 12;
  size_t base = (size_t)bh*NHASH*T_SZ + t;
  float l0 = lse[base];
  float l1 = lse[base + T_SZ];
  float l2 = lse[base + 2*T_SZ];
  float l3 = lse[base + 3*T_SZ];
  float M = fmaxf(fmaxf(l0,l1), fmaxf(l2,l3));
  float e0 = __expf(l0-M), e1 = __expf(l1-M), e2 = __expf(l2-M), e3 = __expf(l3-M);
  float inv = 1.0f/(e0+e1+e2+e3);
  float w0=e0*inv, w1=e1*inv, w2=e2*inv, w3=e3*inv;
  const _Float16* r0 = o_f16 + base*DH;
  const _Float16* r1 = r0 + (size_t)T_SZ*DH;
  const _Float16* r2 = r1 + (size_t)T_SZ*DH;
  const _Float16* r3 = r2 + (size_t)T_SZ*DH;
  int b = bh >> 3, head = bh & 7;
  float* xr = X + ((size_t)b*T_SZ + t)*DMODEL + head*DH;
  for (int d=0; d<64; d++){
    xr[d] = w0*(float)r0[d] + w1*(float)r1[d] + w2*(float)r2[d] + w3*(float)r3[d];
  }
}

// ---------------- K6: output projection X @ W_out + b_out (f32) ----------
__global__ __launch_bounds__(256) void k6_out(const float* __restrict__ X,
    const float* __restrict__ Wout, const float* __restrict__ bout,
    float* __restrict__ out)
{
  __shared__ float xs[8*512];
  int tid = threadIdx.x, blk = blockIdx.x;
  const float4* xsrc = (const float4*)(X + (size_t)blk*8*512);
  float4* xs4 = (float4*)xs;
  #pragma unroll
  for (int k=0;k<4;k++) xs4[tid + k*256] = xsrc[tid + k*256];
  __syncthreads();
  float a0[8], a1[8];
  #pragma unroll
  for (int r=0;r<8;r++){ a0[r]=0.f; a1[r]=0.f; }
  const float2* w2 = (const float2*)Wout;
  for (int d=0; d<512; d++){
    float2 w = w2[d*256 + tid];
    #pragma unroll
    for (int r=0;r<8;r++){
      float x = xs[r*512+d];
      a0[r] += x*w.x; a1[r] += x*w.y;
    }
  }
  int j0 = 2*tid;
  float b0 = bout[j0], b1 = bout[j0+1];
  #pragma unroll
  for (int r=0;r<8;r++){
    float2 res; res.x = a0[r]+b0; res.y = a1[r]+b1;
    *((float2*)(out + ((size_t)(blk*8+r)*512 + j0))) = res;
  }
}

// ---------------- launch ----------------
extern "C" void kernel_launch(void* const* d_in, const int* in_sizes, int n_in,
                              void* d_out, int out_size, void* d_ws, size_t ws_size,
                              hipStream_t stream) {
  const float* queries = (const float*)d_in[0];
  const float* Wqk     = (const float*)d_in[3];
  const float* Wv      = (const float*)d_in[4];
  const float* Wout    = (const float*)d_in[5];
  const float* bout    = (const float*)d_in[6];
  const float* rot     = (const float*)d_in[7];
  float* out = (float*)d_out;

  // workspace layout (bytes)
  const size_t SZ_F32 = (size_t)BH*T_SZ*DH*4;     // 33,554,432 (qk32 / v32 / X each)
  const size_t OFS_QK32   = 0;
  const size_t OFS_V32    = OFS_QK32 + SZ_F32;
  const size_t OFS_X      = OFS_V32  + SZ_F32;
  const size_t OFS_BIG    = OFS_X    + SZ_F32;     // qk64 (f64) aliased with o_rounds (f16), both 67,108,864 B
  const size_t SZ_BIG     = (size_t)BH*T_SZ*DH*8;
  const size_t OFS_BUCKET = OFS_BIG + SZ_BIG;
  const size_t OFS_HIST   = OFS_BUCKET + (size_t)BH*NHASH*T_SZ*2;
  const size_t OFS_STARTS = OFS_HIST   + (size_t)BH*NBUCK*4;
  const size_t OFS_ST     = OFS_STARTS + (size_t)BH*NBUCK*4;
  const size_t OFS_LSE    = OFS_ST     + (size_t)BH*TOT*4;
  const size_t WS_NEEDED  = OFS_LSE    + (size_t)BH*NHASH*T_SZ*4;
  if (ws_size < WS_NEEDED) return;

  char* ws = (char*)d_ws;
  float*    qk32   = (float*)(ws + OFS_QK32);
  float*    v32    = (float*)(ws + OFS_V32);
  float*    X      = (float*)(ws + OFS_X);
  double*   qk64   = (double*)(ws + OFS_BIG);
  _Float16* o_f16  = (_Float16*)(ws + OFS_BIG);   // alias: qk64 dead before K4 writes o
  unsigned short* bucket = (unsigned short*)(ws + OFS_BUCKET);
  int*      hist   = (int*)(ws + OFS_HIST);
  int*      starts = (int*)(ws + OFS_STARTS);
  int*      st     = (int*)(ws + OFS_ST);
  float*    lse    = (float*)(ws + OFS_LSE);

  k0_zero   <<<BH, 256, 0, stream>>>(hist);
  k1_qkv    <<<(B_SZ*T_SZ)/8, 256, 0, stream>>>(queries, Wqk, Wv, qk32, v32, qk64);
  k2_hash   <<<(BH*NHASH*T_SZ)/256, 256, 0, stream>>>(qk64, rot, bucket, hist);
  k3_scan   <<<BH, 256, 0, stream>>>(hist, starts);
  k3b_scatter<<<BH*NBUCK, 64, 0, stream>>>(bucket, starts, st);
  k4_attn   <<<BH*256, 64, 0, stream>>>(qk32, v32, st, lse, o_f16);
  k5_comb   <<<(BH*T_SZ)/256, 256, 0, stream>>>(lse, o_f16, X);
  k6_out    <<<(B_SZ*T_SZ)/8, 256, 0, stream>>>(X, Wout, bout, out);
}

// Round 3
// 1117.954 us; speedup vs baseline: 2.1535x; 2.1535x over previous
//
#include <hip/hip_runtime.h>

typedef unsigned int uint32;
typedef _Float16 f16;
typedef _Float16 f16x8 __attribute__((ext_vector_type(8)));
typedef float f32x4 __attribute__((ext_vector_type(4)));

#define B_SZ 4
#define T_SZ 4096
#define DMODEL 512
#define NHEAD 8
#define DH 64
#define NHASH 4
#define BH (B_SZ*NHEAD)      // 32
#define NBUCK 256            // global buckets per bh row (4 rounds * 64)
#define TOT (NHASH*T_SZ)     // 16384

#define KSTRIDE 72           // f16 elems per k_lds row (128B data + pad, 16B aligned)
#define PSTRIDE 136          // f16 elems per p_lds/vT row (256B data + pad, 16B aligned)

// ---------------- K0: zero histogram ----------------
__global__ void k0_zero(int* hist){ hist[blockIdx.x*256 + threadIdx.x] = 0; }

// ---------------- K1: qk (f64) + v GEMMs -> qk16/v16 (f16) + qk64 ----------
__global__ __launch_bounds__(256) void k1_qkv(const float* __restrict__ qin,
    const float* __restrict__ Wqk, const float* __restrict__ Wv,
    f16* __restrict__ qk16, f16* __restrict__ v16, double* __restrict__ qk64)
{
  __shared__ float qs[8*512];
  int tid = threadIdx.x, blk = blockIdx.x;
  int tok0 = blk*8;
  const float4* src = (const float4*)(qin + (size_t)tok0*512);
  float4* qs4 = (float4*)qs;
  #pragma unroll
  for (int k=0;k<4;k++) qs4[tid + k*256] = src[tid + k*256];
  __syncthreads();
  double aq0[8], aq1[8]; float av0[8], av1[8];
  #pragma unroll
  for (int r=0;r<8;r++){ aq0[r]=0.0; aq1[r]=0.0; av0[r]=0.f; av1[r]=0.f; }
  const float2* wq2 = (const float2*)Wqk;
  const float2* wv2 = (const float2*)Wv;
  for (int d=0; d<512; d++){
    float2 wq = wq2[d*256 + tid];
    float2 wv = wv2[d*256 + tid];
    double dq0 = (double)wq.x, dq1 = (double)wq.y;
    #pragma unroll
    for (int r=0;r<8;r++){
      float x = qs[r*512+d];
      double xd = (double)x;
      aq0[r] += xd*dq0; aq1[r] += xd*dq1;
      av0[r] += x*wv.x; av1[r] += x*wv.y;
    }
  }
  int j0 = 2*tid;
  int head = j0 >> 6, dd = j0 & 63;
  #pragma unroll
  for (int r=0;r<8;r++){
    int tok = tok0 + r; int b = tok >> 12; int tp = tok & 4095;
    size_t idx = ((size_t)(b*NHEAD+head)*T_SZ + tp)*DH + dd;
    union { f16 h[2]; uint32 u; } pq, pv;
    pq.h[0] = (f16)((float)aq0[r]); pq.h[1] = (f16)((float)aq1[r]);
    pv.h[0] = (f16)av0[r];          pv.h[1] = (f16)av1[r];
    *(uint32*)&qk16[idx] = pq.u;
    *(uint32*)&v16[idx]  = pv.u;
    qk64[idx] = aq0[r];   qk64[idx+1] = aq1[r];
  }
}

// ---------------- K2: LSH hashing (f64) + histogram ----------------
__global__ __launch_bounds__(256) void k2_hash(const double* __restrict__ qk64,
    const float* __restrict__ rot, unsigned short* __restrict__ bucket, int* __restrict__ hist)
{
  int gid = blockIdx.x*256 + threadIdx.x;  // [0, BH*NHASH*T)
  int t = gid & (T_SZ-1);
  int h = (gid >> 12) & 3;
  int bh = gid >> 14;
  const double* row = qk64 + ((size_t)bh*T_SZ + t)*DH;
  double acc[32];
  #pragma unroll
  for (int i=0;i<32;i++) acc[i]=0.0;
  for (int dd=0; dd<64; dd++){
    double q = row[dd];
    const float* rp = rot + dd*(NHASH*32) + h*32;
    #pragma unroll
    for (int i=0;i<32;i++) acc[i] += q * (double)rp[i];
  }
  double best = acc[0]; int bk = 0;
  #pragma unroll
  for (int k=1;k<64;k++){
    double vv = (k<32)? acc[k] : -acc[k-32];
    if (vv > best){ best = vv; bk = k; }
  }
  int g = bk + (h<<6);
  bucket[((bh*NHASH + h)<<12) + t] = (unsigned short)g;
  atomicAdd(&hist[bh*NBUCK + g], 1);
}

// ---------------- K3: per-bh exclusive prefix over 256 buckets ----------------
__global__ __launch_bounds__(256) void k3_scan(const int* __restrict__ hist, int* __restrict__ starts){
  __shared__ int s[256];
  int bh = blockIdx.x, tid = threadIdx.x;
  int v = hist[bh*256 + tid];
  s[tid] = v; __syncthreads();
  for (int off=1; off<256; off<<=1){
    int a = (tid >= off) ? s[tid-off] : 0;
    __syncthreads();
    s[tid] += a;
    __syncthreads();
  }
  starts[bh*256 + tid] = s[tid] - v;  // exclusive
}

// ---------------- K3b: stable counting-sort scatter ----------------
__global__ __launch_bounds__(64) void k3b_scatter(const unsigned short* __restrict__ bucket,
    const int* __restrict__ starts, int* __restrict__ st)
{
  int blk = blockIdx.x;
  int bh = blk >> 8; int g = blk & 255; int h = g >> 6;
  int lane = threadIdx.x;
  const unsigned short* brow = bucket + ((bh*NHASH + h)<<12);
  int base = starts[bh*NBUCK + g];
  for (int step=0; step<64; step++){
    int t = step*64 + lane;
    bool pred = (brow[t] == (unsigned short)g);
    unsigned long long mask = __ballot(pred);
    if (pred){
      int off = __popcll(mask & ((1ull<<lane) - 1ull));
      st[bh*TOT + base + off] = t;
    }
    base += __popcll(mask);
  }
}

// ---------------- K4: MFMA chunked LSH attention (one wave per (bh,chunk)) ----
// LDS: [0,18432)   k_lds f16[128][72]  (raw qk rows; later ALIASED by p_lds f16[64][136])
//      [18432, +17408) vT f16[64][136] (V transposed: vT[d][key])
//      [35840, +512)   invnorm f32[128]
//      [36352, +512)   kv_t   i32[128]
__global__ __launch_bounds__(64, 1) void k4_attn(const f16* __restrict__ qk16,
    const f16* __restrict__ v16, const int* __restrict__ st,
    float* __restrict__ lse_out, f16* __restrict__ o_out)
{
  __shared__ __align__(16) char smem[36864];
  f16*   k_lds   = (f16*)smem;
  f16*   p_lds   = (f16*)smem;                    // alias (k dead before P written)
  f16*   vT      = (f16*)(smem + 18432);
  float* invnorm = (float*)(smem + 35840);
  int*   kv_t    = (int*)(smem + 36352);

  int blk = blockIdx.x;
  int bh = blk >> 8; int c = blk & 255;
  int h = c >> 6; int cp = (c + 255) & 255;
  int lane = threadIdx.x;
  int c_lane = lane & 15, quad = lane >> 4;
  const int* strow = st + bh*TOT;

  // ---- gather: lane handles rows {lane, lane+64} ----
  #pragma unroll
  for (int rr=0; rr<2; rr++){
    int row = lane + rr*64;
    int slot = rr ? (cp*64 + lane) : (c*64 + lane);
    int t = strow[slot];
    kv_t[row] = t;
    const f16x8* kr = (const f16x8*)(qk16 + ((size_t)bh*T_SZ + t)*DH);
    const f16x8* vr = (const f16x8*)(v16  + ((size_t)bh*T_SZ + t)*DH);
    f16x8 kv[8], vv[8];
    float ss = 0.f;
    #pragma unroll
    for (int i=0;i<8;i++){
      f16x8 x = kr[i]; kv[i] = x;
      vv[i] = vr[i];
      #pragma unroll
      for (int e=0;e<8;e++){ float f = (float)x[e]; ss += f*f; }
    }
    invnorm[row] = 1.0f / fmaxf(sqrtf(ss), 1e-12f);
    f16x8* kd = (f16x8*)&k_lds[row*KSTRIDE];
    #pragma unroll
    for (int i=0;i<8;i++) kd[i] = kv[i];
    #pragma unroll
    for (int i=0;i<8;i++){
      #pragma unroll
      for (int e=0;e<8;e++) vT[(i*8+e)*PSTRIDE + row] = vv[i][e];
    }
  }

  // ---- preload Q A-fragments (raw rows 0..63) ----
  f16x8 aq[4][2];
  #pragma unroll
  for (int mi=0;mi<4;mi++)
    #pragma unroll
    for (int kb=0;kb<2;kb++)
      aq[mi][kb] = *(const f16x8*)&k_lds[(mi*16 + c_lane)*KSTRIDE + kb*32 + quad*8];

  // ---- S = Q * K_hat^T  (64x128), tiles: mi 0..3, ni 0..7 ----
  f32x4 accS[4][8];
  #pragma unroll
  for (int mi=0;mi<4;mi++)
    #pragma unroll
    for (int ni=0;ni<8;ni++)
      accS[mi][ni] = (f32x4){0.f,0.f,0.f,0.f};

  #pragma unroll
  for (int ni=0;ni<8;ni++){
    int rowb = ni*16 + c_lane;
    f16 sc = (f16)invnorm[rowb];
    f16x8 b0 = *(const f16x8*)&k_lds[rowb*KSTRIDE + 0*32 + quad*8];
    f16x8 b1 = *(const f16x8*)&k_lds[rowb*KSTRIDE + 1*32 + quad*8];
    b0 *= sc; b1 *= sc;
    #pragma unroll
    for (int mi=0;mi<4;mi++){
      accS[mi][ni] = __builtin_amdgcn_mfma_f32_16x16x32_f16(aq[mi][0], b0, accS[mi][ni], 0,0,0);
      accS[mi][ni] = __builtin_amdgcn_mfma_f32_16x16x32_f16(aq[mi][1], b1, accS[mi][ni], 0,0,0);
    }
  }

  // ---- softmax over 128 keys per row ----
  int tq[4][4];
  #pragma unroll
  for (int mi=0;mi<4;mi++)
    #pragma unroll
    for (int r=0;r<4;r++) tq[mi][r] = kv_t[mi*16 + quad*4 + r];
  int tk[8];
  #pragma unroll
  for (int ni=0;ni<8;ni++) tk[ni] = kv_t[ni*16 + c_lane];

  float mrow[4][4], lrow[4][4];
  #pragma unroll
  for (int mi=0;mi<4;mi++){
    #pragma unroll
    for (int r=0;r<4;r++){
      float mx = -1e30f;
      #pragma unroll
      for (int ni=0;ni<8;ni++){
        float s = accS[mi][ni][r] * 0.125f;
        if (tk[ni] == tq[mi][r]) s = -50000.0f;
        accS[mi][ni][r] = s;
        mx = fmaxf(mx, s);
      }
      mx = fmaxf(mx, __shfl_xor(mx, 1));
      mx = fmaxf(mx, __shfl_xor(mx, 2));
      mx = fmaxf(mx, __shfl_xor(mx, 4));
      mx = fmaxf(mx, __shfl_xor(mx, 8));
      mrow[mi][r] = mx;
      float ls = 0.f;
      #pragma unroll
      for (int ni=0;ni<8;ni++){
        float e = __expf(accS[mi][ni][r] - mx);
        accS[mi][ni][r] = e;
        ls += e;
      }
      ls += __shfl_xor(ls, 1);
      ls += __shfl_xor(ls, 2);
      ls += __shfl_xor(ls, 4);
      ls += __shfl_xor(ls, 8);
      lrow[mi][r] = ls;
    }
  }

  // ---- write P (f16) into LDS (aliases dead K buffer) ----
  #pragma unroll
  for (int mi=0;mi<4;mi++)
    #pragma unroll
    for (int ni=0;ni<8;ni++)
      #pragma unroll
      for (int r=0;r<4;r++)
        p_lds[(mi*16 + quad*4 + r)*PSTRIDE + ni*16 + c_lane] = (f16)accS[mi][ni][r];

  // ---- preload V^T B-fragments ----
  f16x8 bv[4][4];
  #pragma unroll
  for (int ni2=0;ni2<4;ni2++)
    #pragma unroll
    for (int kb=0;kb<4;kb++)
      bv[ni2][kb] = *(const f16x8*)&vT[(ni2*16 + c_lane)*PSTRIDE + kb*32 + quad*8];

  // ---- O = P * V  (64x64), write out per m-tile ----
  size_t rowbase = (size_t)(bh*NHASH + h)*T_SZ;
  #pragma unroll
  for (int mi=0;mi<4;mi++){
    f16x8 pa[4];
    #pragma unroll
    for (int kb=0;kb<4;kb++)
      pa[kb] = *(const f16x8*)&p_lds[(mi*16 + c_lane)*PSTRIDE + kb*32 + quad*8];
    f32x4 accO[4];
    #pragma unroll
    for (int ni2=0;ni2<4;ni2++){
      accO[ni2] = (f32x4){0.f,0.f,0.f,0.f};
      #pragma unroll
      for (int kb=0;kb<4;kb++)
        accO[ni2] = __builtin_amdgcn_mfma_f32_16x16x32_f16(pa[kb], bv[ni2][kb], accO[ni2], 0,0,0);
    }
    #pragma unroll
    for (int r=0;r<4;r++){
      int tqi = tq[mi][r];
      float invl = 1.0f / lrow[mi][r];
      f16* orow = o_out + (rowbase + tqi)*DH;
      #pragma unroll
      for (int ni2=0;ni2<4;ni2++)
        orow[ni2*16 + c_lane] = (f16)(accO[ni2][r] * invl);
      if (c_lane == 0)
        lse_out[rowbase + tqi] = mrow[mi][r] + logf(lrow[mi][r]);
    }
  }
}

// ---------------- K5: combine hash rounds, unmerge heads ----------------
__global__ __launch_bounds__(256) void k5_comb(const float* __restrict__ lse,
    const f16* __restrict__ o_f16, float* __restrict__ X)
{
  int gid = blockIdx.x*256 + threadIdx.x;  // [0, BH*T)
  int t = gid & (T_SZ-1);
  int bh = gid >> 12;
  size_t base = (size_t)bh*NHASH*T_SZ + t;
  float l0 = lse[base];
  float l1 = lse[base + T_SZ];
  float l2 = lse[base + 2*T_SZ];
  float l3 = lse[base + 3*T_SZ];
  float M = fmaxf(fmaxf(l0,l1), fmaxf(l2,l3));
  float e0 = __expf(l0-M), e1 = __expf(l1-M), e2 = __expf(l2-M), e3 = __expf(l3-M);
  float inv = 1.0f/(e0+e1+e2+e3);
  float w0=e0*inv, w1=e1*inv, w2=e2*inv, w3=e3*inv;
  const f16* r0 = o_f16 + base*DH;
  const f16* r1 = r0 + (size_t)T_SZ*DH;
  const f16* r2 = r1 + (size_t)T_SZ*DH;
  const f16* r3 = r2 + (size_t)T_SZ*DH;
  int b = bh >> 3, head = bh & 7;
  float* xr = X + ((size_t)b*T_SZ + t)*DMODEL + head*DH;
  for (int d=0; d<64; d++){
    xr[d] = w0*(float)r0[d] + w1*(float)r1[d] + w2*(float)r2[d] + w3*(float)r3[d];
  }
}

// ---------------- K6: output projection X @ W_out + b_out (f32) ----------
__global__ __launch_bounds__(256) void k6_out(const float* __restrict__ X,
    const float* __restrict__ Wout, const float* __restrict__ bout,
    float* __restrict__ out)
{
  __shared__ float xs[8*512];
  int tid = threadIdx.x, blk = blockIdx.x;
  const float4* xsrc = (const float4*)(X + (size_t)blk*8*512);
  float4* xs4 = (float4*)xs;
  #pragma unroll
  for (int k=0;k<4;k++) xs4[tid + k*256] = xsrc[tid + k*256];
  __syncthreads();
  float a0[8], a1[8];
  #pragma unroll
  for (int r=0;r<8;r++){ a0[r]=0.f; a1[r]=0.f; }
  const float2* w2 = (const float2*)Wout;
  for (int d=0; d<512; d++){
    float2 w = w2[d*256 + tid];
    #pragma unroll
    for (int r=0;r<8;r++){
      float x = xs[r*512+d];
      a0[r] += x*w.x; a1[r] += x*w.y;
    }
  }
  int j0 = 2*tid;
  float b0 = bout[j0], b1 = bout[j0+1];
  #pragma unroll
  for (int r=0;r<8;r++){
    float2 res; res.x = a0[r]+b0; res.y = a1[r]+b1;
    *((float2*)(out + ((size_t)(blk*8+r)*512 + j0))) = res;
  }
}

// ---------------- launch ----------------
extern "C" void kernel_launch(void* const* d_in, const int* in_sizes, int n_in,
                              void* d_out, int out_size, void* d_ws, size_t ws_size,
                              hipStream_t stream) {
  const float* queries = (const float*)d_in[0];
  const float* Wqk     = (const float*)d_in[3];
  const float* Wv      = (const float*)d_in[4];
  const float* Wout    = (const float*)d_in[5];
  const float* bout    = (const float*)d_in[6];
  const float* rot     = (const float*)d_in[7];
  float* out = (float*)d_out;

  const size_t SZ_F16   = (size_t)BH*T_SZ*DH*2;   // 16 MB
  const size_t SZ_X     = (size_t)BH*T_SZ*DH*4;   // 32 MB
  const size_t SZ_BIG   = (size_t)BH*T_SZ*DH*8;   // 64 MB (qk64 f64 / o_rounds f16 alias)
  const size_t OFS_QK16   = 0;
  const size_t OFS_V16    = OFS_QK16 + SZ_F16;
  const size_t OFS_X      = OFS_V16  + SZ_F16;
  const size_t OFS_BIG    = OFS_X    + SZ_X;
  const size_t OFS_BUCKET = OFS_BIG + SZ_BIG;
  const size_t OFS_HIST   = OFS_BUCKET + (size_t)BH*NHASH*T_SZ*2;
  const size_t OFS_STARTS = OFS_HIST   + (size_t)BH*NBUCK*4;
  const size_t OFS_ST     = OFS_STARTS + (size_t)BH*NBUCK*4;
  const size_t OFS_LSE    = OFS_ST     + (size_t)BH*TOT*4;
  const size_t WS_NEEDED  = OFS_LSE    + (size_t)BH*NHASH*T_SZ*4;
  if (ws_size < WS_NEEDED) return;

  char* ws = (char*)d_ws;
  f16*      qk16   = (f16*)(ws + OFS_QK16);
  f16*      v16    = (f16*)(ws + OFS_V16);
  float*    X      = (float*)(ws + OFS_X);
  double*   qk64   = (double*)(ws + OFS_BIG);
  f16*      o_f16  = (f16*)(ws + OFS_BIG);   // alias: qk64 dead before K4 writes o
  unsigned short* bucket = (unsigned short*)(ws + OFS_BUCKET);
  int*      hist   = (int*)(ws + OFS_HIST);
  int*      starts = (int*)(ws + OFS_STARTS);
  int*      st     = (int*)(ws + OFS_ST);
  float*    lse    = (float*)(ws + OFS_LSE);

  k0_zero   <<<BH, 256, 0, stream>>>(hist);
  k1_qkv    <<<(B_SZ*T_SZ)/8, 256, 0, stream>>>(queries, Wqk, Wv, qk16, v16, qk64);
  k2_hash   <<<(BH*NHASH*T_SZ)/256, 256, 0, stream>>>(qk64, rot, bucket, hist);
  k3_scan   <<<BH, 256, 0, stream>>>(hist, starts);
  k3b_scatter<<<BH*NBUCK, 64, 0, stream>>>(bucket, starts, st);
  k4_attn   <<<BH*256, 64, 0, stream>>>(qk16, v16, st, lse, o_f16);
  k5_comb   <<<(BH*T_SZ)/256, 256, 0, stream>>>(lse, o_f16, X);
  k6_out    <<<(B_SZ*T_SZ)/8, 256, 0, stream>>>(X, Wout, bout, out);
}

// Round 4
// 1022.990 us; speedup vs baseline: 2.3534x; 1.0928x over previous
//
#include <hip/hip_runtime.h>

typedef unsigned int uint32;
typedef _Float16 f16;
typedef _Float16 f16x8 __attribute__((ext_vector_type(8)));
typedef float f32x4 __attribute__((ext_vector_type(4)));

#define B_SZ 4
#define T_SZ 4096
#define DMODEL 512
#define NHEAD 8
#define DH 64
#define NHASH 4
#define BH (B_SZ*NHEAD)      // 32
#define NBUCK 256            // global buckets per bh row (4 rounds * 64)
#define TOT (NHASH*T_SZ)     // 16384

#define KSTRIDE 72           // f16 elems per k_lds row (128B data + pad, 16B aligned)
#define PSTRIDE 136          // f16 elems per p_lds/vT row (256B data + pad, 16B aligned)

#define AMB_TAU 8e-3f        // ambiguity threshold (× rms of rotated values); worst-case f32 err ~2.9e-3·rms

// ---------------- K0: zero histogram + ambiguity counter ----------------
__global__ void k0_zero(int* hist, int* amb_cnt){
  hist[blockIdx.x*256 + threadIdx.x] = 0;
  if (blockIdx.x == 0 && threadIdx.x == 0) *amb_cnt = 0;
}

// ---------------- K1: qk + v GEMMs, pure f32, 16 tokens/block ----------
// outputs: qk32 (f32, for hashing), qk16/v16 (f16, for attention), layout [bh][t][64]
__global__ __launch_bounds__(256) void k1_qkv(const float* __restrict__ qin,
    const float* __restrict__ Wqk, const float* __restrict__ Wv,
    float* __restrict__ qk32, f16* __restrict__ qk16, f16* __restrict__ v16)
{
  __shared__ float qs[512*16];   // [d][tok], 32 KB
  int tid = threadIdx.x, blk = blockIdx.x;
  int tok0 = blk*16;
  // staging (transposed): thread covers tok=tid&15, d0 = (tid>>4)*4 + k*64
  int stok = tid & 15, sg = tid >> 4;
  #pragma unroll
  for (int k=0;k<8;k++){
    int d0 = sg*4 + k*64;
    float4 x = *(const float4*)(qin + (size_t)(tok0+stok)*DMODEL + d0);
    qs[(d0+0)*16+stok]=x.x; qs[(d0+1)*16+stok]=x.y;
    qs[(d0+2)*16+stok]=x.z; qs[(d0+3)*16+stok]=x.w;
  }
  __syncthreads();
  float aq0[16], aq1[16], av0[16], av1[16];
  #pragma unroll
  for (int r=0;r<16;r++){ aq0[r]=0.f; aq1[r]=0.f; av0[r]=0.f; av1[r]=0.f; }
  const float2* wq2 = (const float2*)Wqk;
  const float2* wv2 = (const float2*)Wv;
  #pragma unroll 2
  for (int d=0; d<512; d++){
    float2 wq = wq2[d*256 + tid];
    float2 wv = wv2[d*256 + tid];
    float4 qa = *(const float4*)&qs[d*16+0];
    float4 qb = *(const float4*)&qs[d*16+4];
    float4 qc = *(const float4*)&qs[d*16+8];
    float4 qd = *(const float4*)&qs[d*16+12];
    float q[16] = {qa.x,qa.y,qa.z,qa.w, qb.x,qb.y,qb.z,qb.w,
                   qc.x,qc.y,qc.z,qc.w, qd.x,qd.y,qd.z,qd.w};
    #pragma unroll
    for (int r=0;r<16;r++){
      aq0[r] = fmaf(q[r], wq.x, aq0[r]);
      aq1[r] = fmaf(q[r], wq.y, aq1[r]);
      av0[r] = fmaf(q[r], wv.x, av0[r]);
      av1[r] = fmaf(q[r], wv.y, av1[r]);
    }
  }
  int j0 = 2*tid;
  int head = j0 >> 6, dd = j0 & 63;
  #pragma unroll
  for (int r=0;r<16;r++){
    int tok = tok0 + r; int b = tok >> 12; int tp = tok & 4095;
    size_t idx = ((size_t)(b*NHEAD+head)*T_SZ + tp)*DH + dd;
    float2 qv; qv.x = aq0[r]; qv.y = aq1[r];
    *(float2*)&qk32[idx] = qv;
    union { f16 h[2]; uint32 u; } pq, pv;
    pq.h[0] = (f16)aq0[r]; pq.h[1] = (f16)aq1[r];
    pv.h[0] = (f16)av0[r]; pv.h[1] = (f16)av1[r];
    *(uint32*)&qk16[idx] = pq.u;
    *(uint32*)&v16[idx]  = pv.u;
  }
}

// ---------------- K2: LSH hashing (f32) + ambiguity detection ----------------
__global__ __launch_bounds__(256) void k2_hash(const float* __restrict__ qk32,
    const float* __restrict__ rot, unsigned short* __restrict__ bucket, int* __restrict__ hist,
    int* __restrict__ amb_list, int* __restrict__ amb_cnt)
{
  int gid = blockIdx.x*256 + threadIdx.x;  // [0, BH*NHASH*T)
  int t = gid & (T_SZ-1);
  int h = (gid >> 12) & 3;
  int bh = gid >> 14;
  const float* row = qk32 + ((size_t)bh*T_SZ + t)*DH;
  float acc[32];
  #pragma unroll
  for (int i=0;i<32;i++) acc[i]=0.f;
  for (int dd=0; dd<64; dd++){
    float q = row[dd];
    const float* rp = rot + dd*(NHASH*32) + h*32;
    #pragma unroll
    for (int i=0;i<32;i++) acc[i] = fmaf(q, rp[i], acc[i]);
  }
  // argmax + runner-up over [acc, -acc], first occurrence wins; rms for threshold
  float m1 = -1e30f, m2 = -1e30f; int bk = 0;
  float ssq = 0.f;
  #pragma unroll
  for (int k=0;k<64;k++){
    float vv = (k<32)? acc[k] : -acc[k-32];
    if (k<32) ssq = fmaf(acc[k], acc[k], ssq);
    if (vv > m1){ m2 = m1; m1 = vv; bk = k; }
    else if (vv > m2){ m2 = vv; }
  }
  float rms = sqrtf(ssq * (1.0f/32.0f));
  if (m1 - m2 < AMB_TAU * rms){
    int idx = atomicAdd(amb_cnt, 1);
    amb_list[idx] = gid;            // defer to f64 fix kernel
  } else {
    int g = bk + (h<<6);
    bucket[((bh*NHASH + h)<<12) + t] = (unsigned short)g;
    atomicAdd(&hist[bh*NBUCK + g], 1);
  }
}

// ---------------- K2fix: exact f64 recompute for ambiguous decisions ----------
// one wave per case; grid-stride over device-side count (graph-capture safe)
__global__ __launch_bounds__(64) void k2_fix(const float* __restrict__ qin,
    const float* __restrict__ Wqk, const float* __restrict__ rot,
    const int* __restrict__ amb_list, const int* __restrict__ amb_cnt,
    unsigned short* __restrict__ bucket, int* __restrict__ hist)
{
  __shared__ double qk64[64];
  __shared__ double accs[32];
  int n = *amb_cnt;
  int lane = threadIdx.x;
  for (int it = blockIdx.x; it < n; it += gridDim.x){
    int gid = amb_list[it];
    int t = gid & (T_SZ-1);
    int h = (gid >> 12) & 3;
    int bh = gid >> 14;
    int b = bh >> 3, head = bh & 7;
    const float* qrow = qin + ((size_t)b*T_SZ + t)*DMODEL;
    const float* wcol = Wqk + head*64 + lane;
    double s = 0.0;
    #pragma unroll 8
    for (int d=0; d<512; d++)
      s += (double)qrow[d] * (double)wcol[(size_t)d*512];
    qk64[lane] = s;
    __syncthreads();
    if (lane < 32){
      double a = 0.0;
      #pragma unroll 8
      for (int f=0; f<64; f++)
        a += qk64[f] * (double)rot[f*(NHASH*32) + h*32 + lane];
      accs[lane] = a;
    }
    __syncthreads();
    if (lane == 0){
      double best = accs[0]; int bk = 0;
      for (int k=1;k<64;k++){
        double vv = (k<32)? accs[k] : -accs[k-32];
        if (vv > best){ best = vv; bk = k; }
      }
      int g = bk + (h<<6);
      bucket[((bh*NHASH + h)<<12) + t] = (unsigned short)g;
      atomicAdd(&hist[bh*NBUCK + g], 1);
    }
    __syncthreads();
  }
}

// ---------------- K3: per-bh exclusive prefix over 256 buckets ----------------
__global__ __launch_bounds__(256) void k3_scan(const int* __restrict__ hist, int* __restrict__ starts){
  __shared__ int s[256];
  int bh = blockIdx.x, tid = threadIdx.x;
  int v = hist[bh*256 + tid];
  s[tid] = v; __syncthreads();
  for (int off=1; off<256; off<<=1){
    int a = (tid >= off) ? s[tid-off] : 0;
    __syncthreads();
    s[tid] += a;
    __syncthreads();
  }
  starts[bh*256 + tid] = s[tid] - v;  // exclusive
}

// ---------------- K3b: stable counting-sort scatter ----------------
__global__ __launch_bounds__(64) void k3b_scatter(const unsigned short* __restrict__ bucket,
    const int* __restrict__ starts, int* __restrict__ st)
{
  int blk = blockIdx.x;
  int bh = blk >> 8; int g = blk & 255; int h = g >> 6;
  int lane = threadIdx.x;
  const unsigned short* brow = bucket + ((bh*NHASH + h)<<12);
  int base = starts[bh*NBUCK + g];
  for (int step=0; step<64; step++){
    int t = step*64 + lane;
    bool pred = (brow[t] == (unsigned short)g);
    unsigned long long mask = __ballot(pred);
    if (pred){
      int off = __popcll(mask & ((1ull<<lane) - 1ull));
      st[bh*TOT + base + off] = t;
    }
    base += __popcll(mask);
  }
}

// ---------------- K4: MFMA chunked LSH attention (one wave per (bh,chunk)) ----
__global__ __launch_bounds__(64, 1) void k4_attn(const f16* __restrict__ qk16,
    const f16* __restrict__ v16, const int* __restrict__ st,
    float* __restrict__ lse_out, f16* __restrict__ o_out)
{
  __shared__ __align__(16) char smem[36864];
  f16*   k_lds   = (f16*)smem;
  f16*   p_lds   = (f16*)smem;                    // alias (k dead before P written)
  f16*   vT      = (f16*)(smem + 18432);
  float* invnorm = (float*)(smem + 35840);
  int*   kv_t    = (int*)(smem + 36352);

  int blk = blockIdx.x;
  int bh = blk >> 8; int c = blk & 255;
  int h = c >> 6; int cp = (c + 255) & 255;
  int lane = threadIdx.x;
  int c_lane = lane & 15, quad = lane >> 4;
  const int* strow = st + bh*TOT;

  #pragma unroll
  for (int rr=0; rr<2; rr++){
    int row = lane + rr*64;
    int slot = rr ? (cp*64 + lane) : (c*64 + lane);
    int t = strow[slot];
    kv_t[row] = t;
    const f16x8* kr = (const f16x8*)(qk16 + ((size_t)bh*T_SZ + t)*DH);
    const f16x8* vr = (const f16x8*)(v16  + ((size_t)bh*T_SZ + t)*DH);
    f16x8 kv[8], vv[8];
    float ss = 0.f;
    #pragma unroll
    for (int i=0;i<8;i++){
      f16x8 x = kr[i]; kv[i] = x;
      vv[i] = vr[i];
      #pragma unroll
      for (int e=0;e<8;e++){ float f = (float)x[e]; ss += f*f; }
    }
    invnorm[row] = 1.0f / fmaxf(sqrtf(ss), 1e-12f);
    f16x8* kd = (f16x8*)&k_lds[row*KSTRIDE];
    #pragma unroll
    for (int i=0;i<8;i++) kd[i] = kv[i];
    #pragma unroll
    for (int i=0;i<8;i++){
      #pragma unroll
      for (int e=0;e<8;e++) vT[(i*8+e)*PSTRIDE + row] = vv[i][e];
    }
  }

  f16x8 aq[4][2];
  #pragma unroll
  for (int mi=0;mi<4;mi++)
    #pragma unroll
    for (int kb=0;kb<2;kb++)
      aq[mi][kb] = *(const f16x8*)&k_lds[(mi*16 + c_lane)*KSTRIDE + kb*32 + quad*8];

  f32x4 accS[4][8];
  #pragma unroll
  for (int mi=0;mi<4;mi++)
    #pragma unroll
    for (int ni=0;ni<8;ni++)
      accS[mi][ni] = (f32x4){0.f,0.f,0.f,0.f};

  #pragma unroll
  for (int ni=0;ni<8;ni++){
    int rowb = ni*16 + c_lane;
    f16 sc = (f16)invnorm[rowb];
    f16x8 b0 = *(const f16x8*)&k_lds[rowb*KSTRIDE + 0*32 + quad*8];
    f16x8 b1 = *(const f16x8*)&k_lds[rowb*KSTRIDE + 1*32 + quad*8];
    b0 *= sc; b1 *= sc;
    #pragma unroll
    for (int mi=0;mi<4;mi++){
      accS[mi][ni] = __builtin_amdgcn_mfma_f32_16x16x32_f16(aq[mi][0], b0, accS[mi][ni], 0,0,0);
      accS[mi][ni] = __builtin_amdgcn_mfma_f32_16x16x32_f16(aq[mi][1], b1, accS[mi][ni], 0,0,0);
    }
  }

  int tq[4][4];
  #pragma unroll
  for (int mi=0;mi<4;mi++)
    #pragma unroll
    for (int r=0;r<4;r++) tq[mi][r] = kv_t[mi*16 + quad*4 + r];
  int tk[8];
  #pragma unroll
  for (int ni=0;ni<8;ni++) tk[ni] = kv_t[ni*16 + c_lane];

  float mrow[4][4], lrow[4][4];
  #pragma unroll
  for (int mi=0;mi<4;mi++){
    #pragma unroll
    for (int r=0;r<4;r++){
      float mx = -1e30f;
      #pragma unroll
      for (int ni=0;ni<8;ni++){
        float s = accS[mi][ni][r] * 0.125f;
        if (tk[ni] == tq[mi][r]) s = -50000.0f;
        accS[mi][ni][r] = s;
        mx = fmaxf(mx, s);
      }
      mx = fmaxf(mx, __shfl_xor(mx, 1));
      mx = fmaxf(mx, __shfl_xor(mx, 2));
      mx = fmaxf(mx, __shfl_xor(mx, 4));
      mx = fmaxf(mx, __shfl_xor(mx, 8));
      mrow[mi][r] = mx;
      float ls = 0.f;
      #pragma unroll
      for (int ni=0;ni<8;ni++){
        float e = __expf(accS[mi][ni][r] - mx);
        accS[mi][ni][r] = e;
        ls += e;
      }
      ls += __shfl_xor(ls, 1);
      ls += __shfl_xor(ls, 2);
      ls += __shfl_xor(ls, 4);
      ls += __shfl_xor(ls, 8);
      lrow[mi][r] = ls;
    }
  }

  #pragma unroll
  for (int mi=0;mi<4;mi++)
    #pragma unroll
    for (int ni=0;ni<8;ni++)
      #pragma unroll
      for (int r=0;r<4;r++)
        p_lds[(mi*16 + quad*4 + r)*PSTRIDE + ni*16 + c_lane] = (f16)accS[mi][ni][r];

  f16x8 bv[4][4];
  #pragma unroll
  for (int ni2=0;ni2<4;ni2++)
    #pragma unroll
    for (int kb=0;kb<4;kb++)
      bv[ni2][kb] = *(const f16x8*)&vT[(ni2*16 + c_lane)*PSTRIDE + kb*32 + quad*8];

  size_t rowbase = (size_t)(bh*NHASH + h)*T_SZ;
  #pragma unroll
  for (int mi=0;mi<4;mi++){
    f16x8 pa[4];
    #pragma unroll
    for (int kb=0;kb<4;kb++)
      pa[kb] = *(const f16x8*)&p_lds[(mi*16 + c_lane)*PSTRIDE + kb*32 + quad*8];
    f32x4 accO[4];
    #pragma unroll
    for (int ni2=0;ni2<4;ni2++){
      accO[ni2] = (f32x4){0.f,0.f,0.f,0.f};
      #pragma unroll
      for (int kb=0;kb<4;kb++)
        accO[ni2] = __builtin_amdgcn_mfma_f32_16x16x32_f16(pa[kb], bv[ni2][kb], accO[ni2], 0,0,0);
    }
    #pragma unroll
    for (int r=0;r<4;r++){
      int tqi = tq[mi][r];
      float invl = 1.0f / lrow[mi][r];
      f16* orow = o_out + (rowbase + tqi)*DH;
      #pragma unroll
      for (int ni2=0;ni2<4;ni2++)
        orow[ni2*16 + c_lane] = (f16)(accO[ni2][r] * invl);
      if (c_lane == 0)
        lse_out[rowbase + tqi] = mrow[mi][r] + logf(lrow[mi][r]);
    }
  }
}

// ---------------- K5: combine hash rounds, unmerge heads ----------------
__global__ __launch_bounds__(256) void k5_comb(const float* __restrict__ lse,
    const f16* __restrict__ o_f16, float* __restrict__ X)
{
  int gid = blockIdx.x*256 + threadIdx.x;  // [0, BH*T)
  int t = gid & (T_SZ-1);
  int bh = gid >> 12;
  size_t base = (size_t)bh*NHASH*T_SZ + t;
  float l0 = lse[base];
  float l1 = lse[base + T_SZ];
  float l2 = lse[base + 2*T_SZ];
  float l3 = lse[base + 3*T_SZ];
  float M = fmaxf(fmaxf(l0,l1), fmaxf(l2,l3));
  float e0 = __expf(l0-M), e1 = __expf(l1-M), e2 = __expf(l2-M), e3 = __expf(l3-M);
  float inv = 1.0f/(e0+e1+e2+e3);
  float w0=e0*inv, w1=e1*inv, w2=e2*inv, w3=e3*inv;
  const f16* r0 = o_f16 + base*DH;
  const f16* r1 = r0 + (size_t)T_SZ*DH;
  const f16* r2 = r1 + (size_t)T_SZ*DH;
  const f16* r3 = r2 + (size_t)T_SZ*DH;
  int b = bh >> 3, head = bh & 7;
  float* xr = X + ((size_t)b*T_SZ + t)*DMODEL + head*DH;
  for (int d=0; d<64; d++){
    xr[d] = w0*(float)r0[d] + w1*(float)r1[d] + w2*(float)r2[d] + w3*(float)r3[d];
  }
}

// ---------------- K6: output projection X @ W_out + b_out (f32) ----------
__global__ __launch_bounds__(256) void k6_out(const float* __restrict__ X,
    const float* __restrict__ Wout, const float* __restrict__ bout,
    float* __restrict__ out)
{
  __shared__ float xs[8*512];
  int tid = threadIdx.x, blk = blockIdx.x;
  const float4* xsrc = (const float4*)(X + (size_t)blk*8*512);
  float4* xs4 = (float4*)xs;
  #pragma unroll
  for (int k=0;k<4;k++) xs4[tid + k*256] = xsrc[tid + k*256];
  __syncthreads();
  float a0[8], a1[8];
  #pragma unroll
  for (int r=0;r<8;r++){ a0[r]=0.f; a1[r]=0.f; }
  const float2* w2 = (const float2*)Wout;
  for (int d=0; d<512; d++){
    float2 w = w2[d*256 + tid];
    #pragma unroll
    for (int r=0;r<8;r++){
      float x = xs[r*512+d];
      a0[r] += x*w.x; a1[r] += x*w.y;
    }
  }
  int j0 = 2*tid;
  float b0 = bout[j0], b1 = bout[j0+1];
  #pragma unroll
  for (int r=0;r<8;r++){
    float2 res; res.x = a0[r]+b0; res.y = a1[r]+b1;
    *((float2*)(out + ((size_t)(blk*8+r)*512 + j0))) = res;
  }
}

// ---------------- launch ----------------
extern "C" void kernel_launch(void* const* d_in, const int* in_sizes, int n_in,
                              void* d_out, int out_size, void* d_ws, size_t ws_size,
                              hipStream_t stream) {
  const float* queries = (const float*)d_in[0];
  const float* Wqk     = (const float*)d_in[3];
  const float* Wv      = (const float*)d_in[4];
  const float* Wout    = (const float*)d_in[5];
  const float* bout    = (const float*)d_in[6];
  const float* rot     = (const float*)d_in[7];
  float* out = (float*)d_out;

  const size_t SZ_QK32 = (size_t)BH*T_SZ*DH*4;            // 32 MB
  const size_t SZ_F16  = (size_t)BH*T_SZ*DH*2;            // 16 MB
  const size_t SZ_X    = (size_t)BH*T_SZ*DH*4;            // 32 MB
  const size_t SZ_O    = (size_t)BH*NHASH*T_SZ*DH*2;      // 64 MB
  const size_t OFS_QK32   = 0;
  const size_t OFS_QK16   = OFS_QK32 + SZ_QK32;
  const size_t OFS_V16    = OFS_QK16 + SZ_F16;
  const size_t OFS_X      = OFS_V16  + SZ_F16;
  const size_t OFS_O      = OFS_X    + SZ_X;
  const size_t OFS_BUCKET = OFS_O    + SZ_O;
  const size_t OFS_HIST   = OFS_BUCKET + (size_t)BH*NHASH*T_SZ*2;
  const size_t OFS_STARTS = OFS_HIST   + (size_t)BH*NBUCK*4;
  const size_t OFS_ST     = OFS_STARTS + (size_t)BH*NBUCK*4;
  const size_t OFS_LSE    = OFS_ST     + (size_t)BH*TOT*4;
  const size_t OFS_AMB    = OFS_LSE    + (size_t)BH*NHASH*T_SZ*4;
  const size_t OFS_CNT    = OFS_AMB    + (size_t)BH*NHASH*T_SZ*4;
  const size_t WS_NEEDED  = OFS_CNT    + 256;
  if (ws_size < WS_NEEDED) return;

  char* ws = (char*)d_ws;
  float*    qk32   = (float*)(ws + OFS_QK32);
  f16*      qk16   = (f16*)(ws + OFS_QK16);
  f16*      v16    = (f16*)(ws + OFS_V16);
  float*    X      = (float*)(ws + OFS_X);
  f16*      o_f16  = (f16*)(ws + OFS_O);
  unsigned short* bucket = (unsigned short*)(ws + OFS_BUCKET);
  int*      hist   = (int*)(ws + OFS_HIST);
  int*      starts = (int*)(ws + OFS_STARTS);
  int*      st     = (int*)(ws + OFS_ST);
  float*    lse    = (float*)(ws + OFS_LSE);
  int*      amb    = (int*)(ws + OFS_AMB);
  int*      cnt    = (int*)(ws + OFS_CNT);

  k0_zero   <<<BH, 256, 0, stream>>>(hist, cnt);
  k1_qkv    <<<(B_SZ*T_SZ)/16, 256, 0, stream>>>(queries, Wqk, Wv, qk32, qk16, v16);
  k2_hash   <<<(BH*NHASH*T_SZ)/256, 256, 0, stream>>>(qk32, rot, bucket, hist, amb, cnt);
  k2_fix    <<<2048, 64, 0, stream>>>(queries, Wqk, rot, amb, cnt, bucket, hist);
  k3_scan   <<<BH, 256, 0, stream>>>(hist, starts);
  k3b_scatter<<<BH*NBUCK, 64, 0, stream>>>(bucket, starts, st);
  k4_attn   <<<BH*256, 64, 0, stream>>>(qk16, v16, st, lse, o_f16);
  k5_comb   <<<(BH*T_SZ)/256, 256, 0, stream>>>(lse, o_f16, X);
  k6_out    <<<(B_SZ*T_SZ)/8, 256, 0, stream>>>(X, Wout, bout, out);
}

// Round 5
// 761.842 us; speedup vs baseline: 3.1601x; 1.3428x over previous
//
#include <hip/hip_runtime.h>

typedef unsigned int uint32;
typedef _Float16 f16;
typedef _Float16 f16x8 __attribute__((ext_vector_type(8)));
typedef float f32x4 __attribute__((ext_vector_type(4)));

#define B_SZ 4
#define T_SZ 4096
#define DMODEL 512
#define NHEAD 8
#define DH 64
#define NHASH 4
#define BH (B_SZ*NHEAD)      // 32
#define NBUCK 256
#define TOT (NHASH*T_SZ)     // 16384
#define M_TOK (B_SZ*T_SZ)    // 16384

#define KSTRIDE 72           // f16 elems per LDS row (128B data + 16B pad); 144B row pitch is 16B-aligned
#define PSTRIDE 136

#define AMB_TAU 8e-3f

// ---------------- K0: zero histogram + ambiguity counter ----------------
__global__ void k0_zero(int* hist, int* amb_cnt){
  hist[blockIdx.x*256 + threadIdx.x] = 0;
  if (blockIdx.x == 0 && threadIdx.x == 0) *amb_cnt = 0;
}

// ---------------- KW: transpose + split W matrices into Wt[n][k] f16 hi/lo ----
// n-glob: [0,512)=Wqk col, [512,1024)=Wv col, [1024,1536)=Wout col
__global__ __launch_bounds__(256) void kw_t(const float* __restrict__ Wqk,
    const float* __restrict__ Wv, const float* __restrict__ Wout,
    f16* __restrict__ Wth, f16* __restrict__ Wtl)
{
  int gid = blockIdx.x*256 + threadIdx.x;   // [0, 1536*512)
  int n = gid >> 9, k = gid & 511;
  int sel = n >> 9, col = n & 511;
  const float* src = (sel==0)? Wqk : (sel==1)? Wv : Wout;
  float v = src[(size_t)k*512 + col];
  f16 h = (f16)v;
  Wth[gid] = h;
  Wtl[gid] = (f16)(v - (float)h);
}

// ---------------- K1a: split queries (f32) -> A_hi/A_lo (f16) ----------------
__global__ __launch_bounds__(256) void k1a_split(const float* __restrict__ qin,
    f16* __restrict__ Ah, f16* __restrict__ Al)
{
  size_t gid = (size_t)blockIdx.x*256 + threadIdx.x;   // handles 8 floats
  const float4* src = (const float4*)(qin) + gid*2;
  float4 x0 = src[0], x1 = src[1];
  float v[8] = {x0.x,x0.y,x0.z,x0.w, x1.x,x1.y,x1.z,x1.w};
  f16x8 h, l;
  #pragma unroll
  for (int e=0;e<8;e++){ f16 hh=(f16)v[e]; h[e]=hh; l[e]=(f16)(v[e]-(float)hh); }
  ((f16x8*)Ah)[gid] = h;
  ((f16x8*)Al)[gid] = l;
}

// ---------------- G1: split-f16 MFMA GEMM  qk|v = queries @ [Wqk|Wv] ---------
// M=16384, N=1024, K=512; 128x128 tile, 4 waves (2x2 of 64x64)
__global__ __launch_bounds__(256) void g_qkv(const f16* __restrict__ Ah,
    const f16* __restrict__ Al, const f16* __restrict__ Wth, const f16* __restrict__ Wtl,
    float* __restrict__ qk32, f16* __restrict__ qk16, f16* __restrict__ v16)
{
  __shared__ f16 ah[128*KSTRIDE], al[128*KSTRIDE], bh[128*KSTRIDE], bl[128*KSTRIDE];
  int tid = threadIdx.x;
  int m0 = blockIdx.x*128, n0 = blockIdx.y*128;
  int w = tid >> 6, lane = tid & 63;
  int wm = w >> 1, wn = w & 1;
  int c_lane = lane & 15, quad = lane >> 4;

  f32x4 acc[4][4];
  #pragma unroll
  for (int mi=0;mi<4;mi++)
    #pragma unroll
    for (int ni=0;ni<4;ni++) acc[mi][ni] = (f32x4){0.f,0.f,0.f,0.f};

  int sr = tid >> 1, sc = (tid & 1) * 32;
  for (int kc=0; kc<8; kc++){
    int k0 = kc*64;
    {
      const f16x8* pah = (const f16x8*)(Ah + (size_t)(m0+sr)*512 + k0 + sc);
      const f16x8* pal = (const f16x8*)(Al + (size_t)(m0+sr)*512 + k0 + sc);
      const f16x8* pbh = (const f16x8*)(Wth + (size_t)(n0+sr)*512 + k0 + sc);
      const f16x8* pbl = (const f16x8*)(Wtl + (size_t)(n0+sr)*512 + k0 + sc);
      f16x8* dah = (f16x8*)&ah[sr*KSTRIDE + sc];
      f16x8* dal = (f16x8*)&al[sr*KSTRIDE + sc];
      f16x8* dbh = (f16x8*)&bh[sr*KSTRIDE + sc];
      f16x8* dbl = (f16x8*)&bl[sr*KSTRIDE + sc];
      #pragma unroll
      for (int i=0;i<4;i++){ dah[i]=pah[i]; dal[i]=pal[i]; dbh[i]=pbh[i]; dbl[i]=pbl[i]; }
    }
    __syncthreads();
    f16x8 fah[4][2], fal[4][2], fbh[4][2], fbl[4][2];
    #pragma unroll
    for (int i=0;i<4;i++)
      #pragma unroll
      for (int kb=0;kb<2;kb++){
        int ma = (wm*64 + i*16 + c_lane)*KSTRIDE + kb*32 + quad*8;
        int nb = (wn*64 + i*16 + c_lane)*KSTRIDE + kb*32 + quad*8;
        fah[i][kb] = *(const f16x8*)&ah[ma];
        fal[i][kb] = *(const f16x8*)&al[ma];
        fbh[i][kb] = *(const f16x8*)&bh[nb];
        fbl[i][kb] = *(const f16x8*)&bl[nb];
      }
    #pragma unroll
    for (int kb=0;kb<2;kb++)
      #pragma unroll
      for (int p=0;p<3;p++)
        #pragma unroll
        for (int mi=0;mi<4;mi++)
          #pragma unroll
          for (int ni=0;ni<4;ni++){
            f16x8 a = (p==2)? fal[mi][kb] : fah[mi][kb];
            f16x8 b = (p==1)? fbl[ni][kb] : fbh[ni][kb];
            acc[mi][ni] = __builtin_amdgcn_mfma_f32_16x16x32_f16(a, b, acc[mi][ni], 0,0,0);
          }
    __syncthreads();
  }

  // epilogue: n<512 -> qk32+qk16; n>=512 -> v16  (block n-range is uniform)
  #pragma unroll
  for (int mi=0;mi<4;mi++)
    #pragma unroll
    for (int ni=0;ni<4;ni++)
      #pragma unroll
      for (int r=0;r<4;r++){
        int n = n0 + wn*64 + ni*16 + c_lane;
        int tok = m0 + wm*64 + mi*16 + quad*4 + r;
        float val = acc[mi][ni][r];
        int b = tok >> 12, tp = tok & 4095;
        if (n < 512){
          int head = n >> 6, dd = n & 63;
          size_t idx = ((size_t)(b*NHEAD+head)*T_SZ + tp)*DH + dd;
          qk32[idx] = val;
          qk16[idx] = (f16)val;
        } else {
          int j = n - 512, head = j >> 6, dd = j & 63;
          size_t idx = ((size_t)(b*NHEAD+head)*T_SZ + tp)*DH + dd;
          v16[idx] = (f16)val;
        }
      }
}

// ---------------- G2: split-f16 MFMA GEMM  out = X @ Wout + bias -------------
__global__ __launch_bounds__(256) void g_out(const f16* __restrict__ Xh,
    const f16* __restrict__ Xl, const f16* __restrict__ Wth, const f16* __restrict__ Wtl,
    const float* __restrict__ bout, float* __restrict__ out)
{
  __shared__ f16 ah[128*KSTRIDE], al[128*KSTRIDE], bh[128*KSTRIDE], bl[128*KSTRIDE];
  int tid = threadIdx.x;
  int m0 = blockIdx.x*128, n0 = blockIdx.y*128;
  int w = tid >> 6, lane = tid & 63;
  int wm = w >> 1, wn = w & 1;
  int c_lane = lane & 15, quad = lane >> 4;
  const f16* Bh_base = Wth + (size_t)1024*512;   // Wout section
  const f16* Bl_base = Wtl + (size_t)1024*512;

  f32x4 acc[4][4];
  #pragma unroll
  for (int mi=0;mi<4;mi++)
    #pragma unroll
    for (int ni=0;ni<4;ni++) acc[mi][ni] = (f32x4){0.f,0.f,0.f,0.f};

  int sr = tid >> 1, sc = (tid & 1) * 32;
  for (int kc=0; kc<8; kc++){
    int k0 = kc*64;
    {
      const f16x8* pah = (const f16x8*)(Xh + (size_t)(m0+sr)*512 + k0 + sc);
      const f16x8* pal = (const f16x8*)(Xl + (size_t)(m0+sr)*512 + k0 + sc);
      const f16x8* pbh = (const f16x8*)(Bh_base + (size_t)(n0+sr)*512 + k0 + sc);
      const f16x8* pbl = (const f16x8*)(Bl_base + (size_t)(n0+sr)*512 + k0 + sc);
      f16x8* dah = (f16x8*)&ah[sr*KSTRIDE + sc];
      f16x8* dal = (f16x8*)&al[sr*KSTRIDE + sc];
      f16x8* dbh = (f16x8*)&bh[sr*KSTRIDE + sc];
      f16x8* dbl = (f16x8*)&bl[sr*KSTRIDE + sc];
      #pragma unroll
      for (int i=0;i<4;i++){ dah[i]=pah[i]; dal[i]=pal[i]; dbh[i]=pbh[i]; dbl[i]=pbl[i]; }
    }
    __syncthreads();
    f16x8 fah[4][2], fal[4][2], fbh[4][2], fbl[4][2];
    #pragma unroll
    for (int i=0;i<4;i++)
      #pragma unroll
      for (int kb=0;kb<2;kb++){
        int ma = (wm*64 + i*16 + c_lane)*KSTRIDE + kb*32 + quad*8;
        int nb = (wn*64 + i*16 + c_lane)*KSTRIDE + kb*32 + quad*8;
        fah[i][kb] = *(const f16x8*)&ah[ma];
        fal[i][kb] = *(const f16x8*)&al[ma];
        fbh[i][kb] = *(const f16x8*)&bh[nb];
        fbl[i][kb] = *(const f16x8*)&bl[nb];
      }
    #pragma unroll
    for (int kb=0;kb<2;kb++)
      #pragma unroll
      for (int p=0;p<3;p++)
        #pragma unroll
        for (int mi=0;mi<4;mi++)
          #pragma unroll
          for (int ni=0;ni<4;ni++){
            f16x8 a = (p==2)? fal[mi][kb] : fah[mi][kb];
            f16x8 b = (p==1)? fbl[ni][kb] : fbh[ni][kb];
            acc[mi][ni] = __builtin_amdgcn_mfma_f32_16x16x32_f16(a, b, acc[mi][ni], 0,0,0);
          }
    __syncthreads();
  }

  #pragma unroll
  for (int mi=0;mi<4;mi++)
    #pragma unroll
    for (int ni=0;ni<4;ni++){
      int n = n0 + wn*64 + ni*16 + c_lane;
      float bn = bout[n];
      #pragma unroll
      for (int r=0;r<4;r++){
        int tok = m0 + wm*64 + mi*16 + quad*4 + r;
        out[(size_t)tok*512 + n] = acc[mi][ni][r] + bn;
      }
    }
}

// ---------------- K2: LSH hashing (f32) + ambiguity detection ----------------
__global__ __launch_bounds__(256) void k2_hash(const float* __restrict__ qk32,
    const float* __restrict__ rot, unsigned short* __restrict__ bucket, int* __restrict__ hist,
    int* __restrict__ amb_list, int* __restrict__ amb_cnt)
{
  int gid = blockIdx.x*256 + threadIdx.x;
  int t = gid & (T_SZ-1);
  int h = (gid >> 12) & 3;
  int bh = gid >> 14;
  const float* row = qk32 + ((size_t)bh*T_SZ + t)*DH;
  float acc[32];
  #pragma unroll
  for (int i=0;i<32;i++) acc[i]=0.f;
  for (int dd=0; dd<64; dd++){
    float q = row[dd];
    const float* rp = rot + dd*(NHASH*32) + h*32;
    #pragma unroll
    for (int i=0;i<32;i++) acc[i] = fmaf(q, rp[i], acc[i]);
  }
  float m1 = -1e30f, m2 = -1e30f; int bk = 0;
  float ssq = 0.f;
  #pragma unroll
  for (int k=0;k<64;k++){
    float vv = (k<32)? acc[k] : -acc[k-32];
    if (k<32) ssq = fmaf(acc[k], acc[k], ssq);
    if (vv > m1){ m2 = m1; m1 = vv; bk = k; }
    else if (vv > m2){ m2 = vv; }
  }
  float rms = sqrtf(ssq * (1.0f/32.0f));
  if (m1 - m2 < AMB_TAU * rms){
    int idx = atomicAdd(amb_cnt, 1);
    amb_list[idx] = gid;
  } else {
    int g = bk + (h<<6);
    bucket[((bh*NHASH + h)<<12) + t] = (unsigned short)g;
    atomicAdd(&hist[bh*NBUCK + g], 1);
  }
}

// ---------------- K2fix: exact f64 recompute for ambiguous decisions ----------
__global__ __launch_bounds__(64) void k2_fix(const float* __restrict__ qin,
    const float* __restrict__ Wqk, const float* __restrict__ rot,
    const int* __restrict__ amb_list, const int* __restrict__ amb_cnt,
    unsigned short* __restrict__ bucket, int* __restrict__ hist)
{
  __shared__ double qk64[64];
  __shared__ double accs[32];
  int n = *amb_cnt;
  int lane = threadIdx.x;
  for (int it = blockIdx.x; it < n; it += gridDim.x){
    int gid = amb_list[it];
    int t = gid & (T_SZ-1);
    int h = (gid >> 12) & 3;
    int bh = gid >> 14;
    int b = bh >> 3, head = bh & 7;
    const float* qrow = qin + ((size_t)b*T_SZ + t)*DMODEL;
    const float* wcol = Wqk + head*64 + lane;
    double s = 0.0;
    #pragma unroll 8
    for (int d=0; d<512; d++)
      s += (double)qrow[d] * (double)wcol[(size_t)d*512];
    qk64[lane] = s;
    __syncthreads();
    if (lane < 32){
      double a = 0.0;
      #pragma unroll 8
      for (int f=0; f<64; f++)
        a += qk64[f] * (double)rot[f*(NHASH*32) + h*32 + lane];
      accs[lane] = a;
    }
    __syncthreads();
    if (lane == 0){
      double best = accs[0]; int bk = 0;
      for (int k=1;k<64;k++){
        double vv = (k<32)? accs[k] : -accs[k-32];
        if (vv > best){ best = vv; bk = k; }
      }
      int g = bk + (h<<6);
      bucket[((bh*NHASH + h)<<12) + t] = (unsigned short)g;
      atomicAdd(&hist[bh*NBUCK + g], 1);
    }
    __syncthreads();
  }
}

// ---------------- K3: per-bh exclusive prefix over 256 buckets ----------------
__global__ __launch_bounds__(256) void k3_scan(const int* __restrict__ hist, int* __restrict__ starts){
  __shared__ int s[256];
  int bh = blockIdx.x, tid = threadIdx.x;
  int v = hist[bh*256 + tid];
  s[tid] = v; __syncthreads();
  for (int off=1; off<256; off<<=1){
    int a = (tid >= off) ? s[tid-off] : 0;
    __syncthreads();
    s[tid] += a;
    __syncthreads();
  }
  starts[bh*256 + tid] = s[tid] - v;
}

// ---------------- K3b: stable counting-sort scatter ----------------
__global__ __launch_bounds__(64) void k3b_scatter(const unsigned short* __restrict__ bucket,
    const int* __restrict__ starts, int* __restrict__ st)
{
  int blk = blockIdx.x;
  int bh = blk >> 8; int g = blk & 255; int h = g >> 6;
  int lane = threadIdx.x;
  const unsigned short* brow = bucket + ((bh*NHASH + h)<<12);
  int base = starts[bh*NBUCK + g];
  for (int step=0; step<64; step++){
    int t = step*64 + lane;
    bool pred = (brow[t] == (unsigned short)g);
    unsigned long long mask = __ballot(pred);
    if (pred){
      int off = __popcll(mask & ((1ull<<lane) - 1ull));
      st[bh*TOT + base + off] = t;
    }
    base += __popcll(mask);
  }
}

// ---------------- K4: MFMA chunked LSH attention (one wave per (bh,chunk)) ----
__global__ __launch_bounds__(64, 1) void k4_attn(const f16* __restrict__ qk16,
    const f16* __restrict__ v16, const int* __restrict__ st,
    float* __restrict__ lse_out, f16* __restrict__ o_out)
{
  __shared__ __align__(16) char smem[36864];
  f16*   k_lds   = (f16*)smem;
  f16*   p_lds   = (f16*)smem;
  f16*   vT      = (f16*)(smem + 18432);
  float* invnorm = (float*)(smem + 35840);
  int*   kv_t    = (int*)(smem + 36352);

  int blk = blockIdx.x;
  int bh = blk >> 8; int c = blk & 255;
  int h = c >> 6; int cp = (c + 255) & 255;
  int lane = threadIdx.x;
  int c_lane = lane & 15, quad = lane >> 4;
  const int* strow = st + bh*TOT;

  #pragma unroll
  for (int rr=0; rr<2; rr++){
    int row = lane + rr*64;
    int slot = rr ? (cp*64 + lane) : (c*64 + lane);
    int t = strow[slot];
    kv_t[row] = t;
    const f16x8* kr = (const f16x8*)(qk16 + ((size_t)bh*T_SZ + t)*DH);
    const f16x8* vr = (const f16x8*)(v16  + ((size_t)bh*T_SZ + t)*DH);
    f16x8 kv[8], vv[8];
    float ss = 0.f;
    #pragma unroll
    for (int i=0;i<8;i++){
      f16x8 x = kr[i]; kv[i] = x;
      vv[i] = vr[i];
      #pragma unroll
      for (int e=0;e<8;e++){ float f = (float)x[e]; ss += f*f; }
    }
    invnorm[row] = 1.0f / fmaxf(sqrtf(ss), 1e-12f);
    f16x8* kd = (f16x8*)&k_lds[row*KSTRIDE];
    #pragma unroll
    for (int i=0;i<8;i++) kd[i] = kv[i];
    #pragma unroll
    for (int i=0;i<8;i++){
      #pragma unroll
      for (int e=0;e<8;e++) vT[(i*8+e)*PSTRIDE + row] = vv[i][e];
    }
  }

  f16x8 aq[4][2];
  #pragma unroll
  for (int mi=0;mi<4;mi++)
    #pragma unroll
    for (int kb=0;kb<2;kb++)
      aq[mi][kb] = *(const f16x8*)&k_lds[(mi*16 + c_lane)*KSTRIDE + kb*32 + quad*8];

  f32x4 accS[4][8];
  #pragma unroll
  for (int mi=0;mi<4;mi++)
    #pragma unroll
    for (int ni=0;ni<8;ni++)
      accS[mi][ni] = (f32x4){0.f,0.f,0.f,0.f};

  #pragma unroll
  for (int ni=0;ni<8;ni++){
    int rowb = ni*16 + c_lane;
    f16 sc = (f16)invnorm[rowb];
    f16x8 b0 = *(const f16x8*)&k_lds[rowb*KSTRIDE + 0*32 + quad*8];
    f16x8 b1 = *(const f16x8*)&k_lds[rowb*KSTRIDE + 1*32 + quad*8];
    b0 *= sc; b1 *= sc;
    #pragma unroll
    for (int mi=0;mi<4;mi++){
      accS[mi][ni] = __builtin_amdgcn_mfma_f32_16x16x32_f16(aq[mi][0], b0, accS[mi][ni], 0,0,0);
      accS[mi][ni] = __builtin_amdgcn_mfma_f32_16x16x32_f16(aq[mi][1], b1, accS[mi][ni], 0,0,0);
    }
  }

  int tq[4][4];
  #pragma unroll
  for (int mi=0;mi<4;mi++)
    #pragma unroll
    for (int r=0;r<4;r++) tq[mi][r] = kv_t[mi*16 + quad*4 + r];
  int tk[8];
  #pragma unroll
  for (int ni=0;ni<8;ni++) tk[ni] = kv_t[ni*16 + c_lane];

  float mrow[4][4], lrow[4][4];
  #pragma unroll
  for (int mi=0;mi<4;mi++){
    #pragma unroll
    for (int r=0;r<4;r++){
      float mx = -1e30f;
      #pragma unroll
      for (int ni=0;ni<8;ni++){
        float s = accS[mi][ni][r] * 0.125f;
        if (tk[ni] == tq[mi][r]) s = -50000.0f;
        accS[mi][ni][r] = s;
        mx = fmaxf(mx, s);
      }
      mx = fmaxf(mx, __shfl_xor(mx, 1));
      mx = fmaxf(mx, __shfl_xor(mx, 2));
      mx = fmaxf(mx, __shfl_xor(mx, 4));
      mx = fmaxf(mx, __shfl_xor(mx, 8));
      mrow[mi][r] = mx;
      float ls = 0.f;
      #pragma unroll
      for (int ni=0;ni<8;ni++){
        float e = __expf(accS[mi][ni][r] - mx);
        accS[mi][ni][r] = e;
        ls += e;
      }
      ls += __shfl_xor(ls, 1);
      ls += __shfl_xor(ls, 2);
      ls += __shfl_xor(ls, 4);
      ls += __shfl_xor(ls, 8);
      lrow[mi][r] = ls;
    }
  }

  #pragma unroll
  for (int mi=0;mi<4;mi++)
    #pragma unroll
    for (int ni=0;ni<8;ni++)
      #pragma unroll
      for (int r=0;r<4;r++)
        p_lds[(mi*16 + quad*4 + r)*PSTRIDE + ni*16 + c_lane] = (f16)accS[mi][ni][r];

  f16x8 bv[4][4];
  #pragma unroll
  for (int ni2=0;ni2<4;ni2++)
    #pragma unroll
    for (int kb=0;kb<4;kb++)
      bv[ni2][kb] = *(const f16x8*)&vT[(ni2*16 + c_lane)*PSTRIDE + kb*32 + quad*8];

  size_t rowbase = (size_t)(bh*NHASH + h)*T_SZ;
  #pragma unroll
  for (int mi=0;mi<4;mi++){
    f16x8 pa[4];
    #pragma unroll
    for (int kb=0;kb<4;kb++)
      pa[kb] = *(const f16x8*)&p_lds[(mi*16 + c_lane)*PSTRIDE + kb*32 + quad*8];
    f32x4 accO[4];
    #pragma unroll
    for (int ni2=0;ni2<4;ni2++){
      accO[ni2] = (f32x4){0.f,0.f,0.f,0.f};
      #pragma unroll
      for (int kb=0;kb<4;kb++)
        accO[ni2] = __builtin_amdgcn_mfma_f32_16x16x32_f16(pa[kb], bv[ni2][kb], accO[ni2], 0,0,0);
    }
    #pragma unroll
    for (int r=0;r<4;r++){
      int tqi = tq[mi][r];
      float invl = 1.0f / lrow[mi][r];
      f16* orow = o_out + (rowbase + tqi)*DH;
      #pragma unroll
      for (int ni2=0;ni2<4;ni2++)
        orow[ni2*16 + c_lane] = (f16)(accO[ni2][r] * invl);
      if (c_lane == 0)
        lse_out[rowbase + tqi] = mrow[mi][r] + logf(lrow[mi][r]);
    }
  }
}

// ---------------- K5: combine hash rounds -> X_hi/X_lo (f16 split) ----------
__global__ __launch_bounds__(256) void k5_comb(const float* __restrict__ lse,
    const f16* __restrict__ o_f16, f16* __restrict__ Xh, f16* __restrict__ Xl)
{
  int gid = blockIdx.x*256 + threadIdx.x;  // [0, BH*T)
  int t = gid & (T_SZ-1);
  int bh = gid >> 12;
  size_t base = (size_t)bh*NHASH*T_SZ + t;
  float l0 = lse[base];
  float l1 = lse[base + T_SZ];
  float l2 = lse[base + 2*T_SZ];
  float l3 = lse[base + 3*T_SZ];
  float M = fmaxf(fmaxf(l0,l1), fmaxf(l2,l3));
  float e0 = __expf(l0-M), e1 = __expf(l1-M), e2 = __expf(l2-M), e3 = __expf(l3-M);
  float inv = 1.0f/(e0+e1+e2+e3);
  float w0=e0*inv, w1=e1*inv, w2=e2*inv, w3=e3*inv;
  const f16x8* r0 = (const f16x8*)(o_f16 + base*DH);
  const f16x8* r1 = (const f16x8*)(o_f16 + (base + (size_t)T_SZ)*DH);
  const f16x8* r2 = (const f16x8*)(o_f16 + (base + (size_t)2*T_SZ)*DH);
  const f16x8* r3 = (const f16x8*)(o_f16 + (base + (size_t)3*T_SZ)*DH);
  int b = bh >> 3, head = bh & 7;
  size_t xofs = ((size_t)(b*T_SZ + t)*DMODEL + head*DH);
  f16x8* xh = (f16x8*)(Xh + xofs);
  f16x8* xl = (f16x8*)(Xl + xofs);
  #pragma unroll
  for (int i=0; i<8; i++){
    f16x8 a = r0[i], bb = r1[i], cc = r2[i], dd = r3[i];
    f16x8 ho, lo;
    #pragma unroll
    for (int e=0;e<8;e++){
      float res = w0*(float)a[e] + w1*(float)bb[e] + w2*(float)cc[e] + w3*(float)dd[e];
      f16 hh = (f16)res;
      ho[e] = hh; lo[e] = (f16)(res - (float)hh);
    }
    xh[i] = ho; xl[i] = lo;
  }
}

// ---------------- launch ----------------
extern "C" void kernel_launch(void* const* d_in, const int* in_sizes, int n_in,
                              void* d_out, int out_size, void* d_ws, size_t ws_size,
                              hipStream_t stream) {
  const float* queries = (const float*)d_in[0];
  const float* Wqk     = (const float*)d_in[3];
  const float* Wv      = (const float*)d_in[4];
  const float* Wout    = (const float*)d_in[5];
  const float* bout    = (const float*)d_in[6];
  const float* rot     = (const float*)d_in[7];
  float* out = (float*)d_out;

  const size_t SZ_QK32 = (size_t)BH*T_SZ*DH*4;        // 32 MB (aliased by X_hi+X_lo)
  const size_t SZ_F16  = (size_t)BH*T_SZ*DH*2;        // 16 MB
  const size_t SZ_WT   = (size_t)1536*512*2;          // 1.5 MB
  const size_t SZ_O    = (size_t)BH*NHASH*T_SZ*DH*2;  // 64 MB
  const size_t OFS_QK32   = 0;                         // qk32; later X_hi(16MB)+X_lo(16MB)
  const size_t OFS_AH     = OFS_QK32 + SZ_QK32;
  const size_t OFS_AL     = OFS_AH   + SZ_F16;
  const size_t OFS_QK16   = OFS_AL   + SZ_F16;
  const size_t OFS_V16    = OFS_QK16 + SZ_F16;
  const size_t OFS_WTH    = OFS_V16  + SZ_F16;
  const size_t OFS_WTL    = OFS_WTH  + SZ_WT;
  const size_t OFS_O      = OFS_WTL  + SZ_WT;
  const size_t OFS_BUCKET = OFS_O    + SZ_O;
  const size_t OFS_HIST   = OFS_BUCKET + (size_t)BH*NHASH*T_SZ*2;
  const size_t OFS_STARTS = OFS_HIST   + (size_t)BH*NBUCK*4;
  const size_t OFS_ST     = OFS_STARTS + (size_t)BH*NBUCK*4;
  const size_t OFS_LSE    = OFS_ST     + (size_t)BH*TOT*4;
  const size_t OFS_AMB    = OFS_LSE    + (size_t)BH*NHASH*T_SZ*4;
  const size_t OFS_CNT    = OFS_AMB    + (size_t)BH*NHASH*T_SZ*4;
  const size_t WS_NEEDED  = OFS_CNT    + 256;
  if (ws_size < WS_NEEDED) return;

  char* ws = (char*)d_ws;
  float*    qk32   = (float*)(ws + OFS_QK32);
  f16*      Xh     = (f16*)(ws + OFS_QK32);            // alias: qk32 dead after k2
  f16*      Xl     = (f16*)(ws + OFS_QK32 + SZ_F16);
  f16*      Ah     = (f16*)(ws + OFS_AH);
  f16*      Al     = (f16*)(ws + OFS_AL);
  f16*      qk16   = (f16*)(ws + OFS_QK16);
  f16*      v16    = (f16*)(ws + OFS_V16);
  f16*      Wth    = (f16*)(ws + OFS_WTH);
  f16*      Wtl    = (f16*)(ws + OFS_WTL);
  f16*      o_f16  = (f16*)(ws + OFS_O);
  unsigned short* bucket = (unsigned short*)(ws + OFS_BUCKET);
  int*      hist   = (int*)(ws + OFS_HIST);
  int*      starts = (int*)(ws + OFS_STARTS);
  int*      st     = (int*)(ws + OFS_ST);
  float*    lse    = (float*)(ws + OFS_LSE);
  int*      amb    = (int*)(ws + OFS_AMB);
  int*      cnt    = (int*)(ws + OFS_CNT);

  k0_zero   <<<BH, 256, 0, stream>>>(hist, cnt);
  kw_t      <<<(1536*512)/256, 256, 0, stream>>>(Wqk, Wv, Wout, Wth, Wtl);
  k1a_split <<<(M_TOK*DMODEL/8)/256, 256, 0, stream>>>(queries, Ah, Al);
  g_qkv     <<<dim3(M_TOK/128, 8), 256, 0, stream>>>(Ah, Al, Wth, Wtl, qk32, qk16, v16);
  k2_hash   <<<(BH*NHASH*T_SZ)/256, 256, 0, stream>>>(qk32, rot, bucket, hist, amb, cnt);
  k2_fix    <<<2048, 64, 0, stream>>>(queries, Wqk, rot, amb, cnt, bucket, hist);
  k3_scan   <<<BH, 256, 0, stream>>>(hist, starts);
  k3b_scatter<<<BH*NBUCK, 64, 0, stream>>>(bucket, starts, st);
  k4_attn   <<<BH*256, 64, 0, stream>>>(qk16, v16, st, lse, o_f16);
  k5_comb   <<<(BH*T_SZ)/256, 256, 0, stream>>>(lse, o_f16, Xh, Xl);
  g_out     <<<dim3(M_TOK/128, 4), 256, 0, stream>>>(Xh, Xl, Wth, Wtl, bout, out);
}

// Round 7
// 725.262 us; speedup vs baseline: 3.3195x; 1.0504x over previous
//
#include <hip/hip_runtime.h>

typedef unsigned int uint32;
typedef _Float16 f16;
typedef _Float16 f16x8 __attribute__((ext_vector_type(8)));
typedef float f32x4 __attribute__((ext_vector_type(4)));

#define B_SZ 4
#define T_SZ 4096
#define DMODEL 512
#define NHEAD 8
#define DH 64
#define NHASH 4
#define BH (B_SZ*NHEAD)      // 32
#define NBUCK 256
#define TOT (NHASH*T_SZ)     // 16384
#define M_TOK (B_SZ*T_SZ)    // 16384

#define KSTRIDE 72           // f16 elems per LDS row (128B data + 16B pad)
#define PSTRIDE 136

#define AMB_TAU 8e-3f

// ---------------- K0: zero histogram + ambiguity counter ----------------
__global__ void k0_zero(int* hist, int* amb_cnt){
  hist[blockIdx.x*256 + threadIdx.x] = 0;
  if (blockIdx.x == 0 && threadIdx.x == 0) *amb_cnt = 0;
}

// ---------------- KW: transpose + split W matrices into Wt[n][k] f16 hi/lo ----
__global__ __launch_bounds__(256) void kw_t(const float* __restrict__ Wqk,
    const float* __restrict__ Wv, const float* __restrict__ Wout,
    f16* __restrict__ Wth, f16* __restrict__ Wtl)
{
  int gid = blockIdx.x*256 + threadIdx.x;   // [0, 1536*512)
  int n = gid >> 9, k = gid & 511;
  int sel = n >> 9, col = n & 511;
  const float* src = (sel==0)? Wqk : (sel==1)? Wv : Wout;
  float v = src[(size_t)k*512 + col];
  f16 h = (f16)v;
  Wth[gid] = h;
  Wtl[gid] = (f16)(v - (float)h);
}

// ---------------- KR: transpose + split rotations into rotT[n=h*32+j][k=dd] --
__global__ __launch_bounds__(256) void kr_t(const float* __restrict__ rot,
    f16* __restrict__ rotTh, f16* __restrict__ rotTl)
{
  int gid = blockIdx.x*256 + threadIdx.x;   // [0, 128*64)
  int n = gid >> 6, dd = gid & 63;
  float v = rot[dd*128 + n];
  f16 h = (f16)v;
  rotTh[gid] = h;
  rotTl[gid] = (f16)(v - (float)h);
}

// ---------------- K1a: split queries (f32) -> A_hi/A_lo (f16) ----------------
__global__ __launch_bounds__(256) void k1a_split(const float* __restrict__ qin,
    f16* __restrict__ Ah, f16* __restrict__ Al)
{
  size_t gid = (size_t)blockIdx.x*256 + threadIdx.x;   // handles 8 floats
  const float4* src = (const float4*)(qin) + gid*2;
  float4 x0 = src[0], x1 = src[1];
  float v[8] = {x0.x,x0.y,x0.z,x0.w, x1.x,x1.y,x1.z,x1.w};
  f16x8 h, l;
  #pragma unroll
  for (int e=0;e<8;e++){ f16 hh=(f16)v[e]; h[e]=hh; l[e]=(f16)(v[e]-(float)hh); }
  ((f16x8*)Ah)[gid] = h;
  ((f16x8*)Al)[gid] = l;
}

// ---------------- G1: split-f16 MFMA GEMM  qk|v = queries @ [Wqk|Wv] ---------
__global__ __launch_bounds__(256) void g_qkv(const f16* __restrict__ Ah,
    const f16* __restrict__ Al, const f16* __restrict__ Wth, const f16* __restrict__ Wtl,
    f16* __restrict__ qk16, f16* __restrict__ qkl, f16* __restrict__ v16)
{
  __shared__ f16 ah[128*KSTRIDE], al[128*KSTRIDE], bh[128*KSTRIDE], bl[128*KSTRIDE];
  int tid = threadIdx.x;
  int m0 = blockIdx.x*128, n0 = blockIdx.y*128;
  int w = tid >> 6, lane = tid & 63;
  int wm = w >> 1, wn = w & 1;
  int c_lane = lane & 15, quad = lane >> 4;

  f32x4 acc[4][4];
  #pragma unroll
  for (int mi=0;mi<4;mi++)
    #pragma unroll
    for (int ni=0;ni<4;ni++) acc[mi][ni] = (f32x4){0.f,0.f,0.f,0.f};

  int sr = tid >> 1, sc = (tid & 1) * 32;
  for (int kc=0; kc<8; kc++){
    int k0 = kc*64;
    {
      const f16x8* pah = (const f16x8*)(Ah + (size_t)(m0+sr)*512 + k0 + sc);
      const f16x8* pal = (const f16x8*)(Al + (size_t)(m0+sr)*512 + k0 + sc);
      const f16x8* pbh = (const f16x8*)(Wth + (size_t)(n0+sr)*512 + k0 + sc);
      const f16x8* pbl = (const f16x8*)(Wtl + (size_t)(n0+sr)*512 + k0 + sc);
      f16x8* dah = (f16x8*)&ah[sr*KSTRIDE + sc];
      f16x8* dal = (f16x8*)&al[sr*KSTRIDE + sc];
      f16x8* dbh = (f16x8*)&bh[sr*KSTRIDE + sc];
      f16x8* dbl = (f16x8*)&bl[sr*KSTRIDE + sc];
      #pragma unroll
      for (int i=0;i<4;i++){ dah[i]=pah[i]; dal[i]=pal[i]; dbh[i]=pbh[i]; dbl[i]=pbl[i]; }
    }
    __syncthreads();
    f16x8 fah[4][2], fal[4][2], fbh[4][2], fbl[4][2];
    #pragma unroll
    for (int i=0;i<4;i++)
      #pragma unroll
      for (int kb=0;kb<2;kb++){
        int ma = (wm*64 + i*16 + c_lane)*KSTRIDE + kb*32 + quad*8;
        int nb = (wn*64 + i*16 + c_lane)*KSTRIDE + kb*32 + quad*8;
        fah[i][kb] = *(const f16x8*)&ah[ma];
        fal[i][kb] = *(const f16x8*)&al[ma];
        fbh[i][kb] = *(const f16x8*)&bh[nb];
        fbl[i][kb] = *(const f16x8*)&bl[nb];
      }
    #pragma unroll
    for (int kb=0;kb<2;kb++)
      #pragma unroll
      for (int p=0;p<3;p++)
        #pragma unroll
        for (int mi=0;mi<4;mi++)
          #pragma unroll
          for (int ni=0;ni<4;ni++){
            f16x8 a = (p==2)? fal[mi][kb] : fah[mi][kb];
            f16x8 b = (p==1)? fbl[ni][kb] : fbh[ni][kb];
            acc[mi][ni] = __builtin_amdgcn_mfma_f32_16x16x32_f16(a, b, acc[mi][ni], 0,0,0);
          }
    __syncthreads();
  }

  // epilogue: n<512 -> qk16(hi)+qkl(lo); n>=512 -> v16
  #pragma unroll
  for (int mi=0;mi<4;mi++)
    #pragma unroll
    for (int ni=0;ni<4;ni++)
      #pragma unroll
      for (int r=0;r<4;r++){
        int n = n0 + wn*64 + ni*16 + c_lane;
        int tok = m0 + wm*64 + mi*16 + quad*4 + r;
        float val = acc[mi][ni][r];
        int b = tok >> 12, tp = tok & 4095;
        if (n < 512){
          int head = n >> 6, dd = n & 63;
          size_t idx = ((size_t)(b*NHEAD+head)*T_SZ + tp)*DH + dd;
          f16 hv = (f16)val;
          qk16[idx] = hv;
          qkl[idx]  = (f16)(val - (float)hv);
        } else {
          int j = n - 512, head = j >> 6, dd = j & 63;
          size_t idx = ((size_t)(b*NHEAD+head)*T_SZ + tp)*DH + dd;
          v16[idx] = (f16)val;
        }
      }
}

// ---------------- G2: split-f16 MFMA GEMM  out = X @ Wout + bias -------------
__global__ __launch_bounds__(256) void g_out(const f16* __restrict__ Xh,
    const f16* __restrict__ Xl, const f16* __restrict__ Wth, const f16* __restrict__ Wtl,
    const float* __restrict__ bout, float* __restrict__ out)
{
  __shared__ f16 ah[128*KSTRIDE], al[128*KSTRIDE], bh[128*KSTRIDE], bl[128*KSTRIDE];
  int tid = threadIdx.x;
  int m0 = blockIdx.x*128, n0 = blockIdx.y*128;
  int w = tid >> 6, lane = tid & 63;
  int wm = w >> 1, wn = w & 1;
  int c_lane = lane & 15, quad = lane >> 4;
  const f16* Bh_base = Wth + (size_t)1024*512;   // Wout section
  const f16* Bl_base = Wtl + (size_t)1024*512;

  f32x4 acc[4][4];
  #pragma unroll
  for (int mi=0;mi<4;mi++)
    #pragma unroll
    for (int ni=0;ni<4;ni++) acc[mi][ni] = (f32x4){0.f,0.f,0.f,0.f};

  int sr = tid >> 1, sc = (tid & 1) * 32;
  for (int kc=0; kc<8; kc++){
    int k0 = kc*64;
    {
      const f16x8* pah = (const f16x8*)(Xh + (size_t)(m0+sr)*512 + k0 + sc);
      const f16x8* pal = (const f16x8*)(Xl + (size_t)(m0+sr)*512 + k0 + sc);
      const f16x8* pbh = (const f16x8*)(Bh_base + (size_t)(n0+sr)*512 + k0 + sc);
      const f16x8* pbl = (const f16x8*)(Bl_base + (size_t)(n0+sr)*512 + k0 + sc);
      f16x8* dah = (f16x8*)&ah[sr*KSTRIDE + sc];
      f16x8* dal = (f16x8*)&al[sr*KSTRIDE + sc];
      f16x8* dbh = (f16x8*)&bh[sr*KSTRIDE + sc];
      f16x8* dbl = (f16x8*)&bl[sr*KSTRIDE + sc];
      #pragma unroll
      for (int i=0;i<4;i++){ dah[i]=pah[i]; dal[i]=pal[i]; dbh[i]=pbh[i]; dbl[i]=pbl[i]; }
    }
    __syncthreads();
    f16x8 fah[4][2], fal[4][2], fbh[4][2], fbl[4][2];
    #pragma unroll
    for (int i=0;i<4;i++)
      #pragma unroll
      for (int kb=0;kb<2;kb++){
        int ma = (wm*64 + i*16 + c_lane)*KSTRIDE + kb*32 + quad*8;
        int nb = (wn*64 + i*16 + c_lane)*KSTRIDE + kb*32 + quad*8;
        fah[i][kb] = *(const f16x8*)&ah[ma];
        fal[i][kb] = *(const f16x8*)&al[ma];
        fbh[i][kb] = *(const f16x8*)&bh[nb];
        fbl[i][kb] = *(const f16x8*)&bl[nb];
      }
    #pragma unroll
    for (int kb=0;kb<2;kb++)
      #pragma unroll
      for (int p=0;p<3;p++)
        #pragma unroll
        for (int mi=0;mi<4;mi++)
          #pragma unroll
          for (int ni=0;ni<4;ni++){
            f16x8 a = (p==2)? fal[mi][kb] : fah[mi][kb];
            f16x8 b = (p==1)? fbl[ni][kb] : fbh[ni][kb];
            acc[mi][ni] = __builtin_amdgcn_mfma_f32_16x16x32_f16(a, b, acc[mi][ni], 0,0,0);
          }
    __syncthreads();
  }

  #pragma unroll
  for (int mi=0;mi<4;mi++)
    #pragma unroll
    for (int ni=0;ni<4;ni++){
      int n = n0 + wn*64 + ni*16 + c_lane;
      float bn = bout[n];
      #pragma unroll
      for (int r=0;r<4;r++){
        int tok = m0 + wm*64 + mi*16 + quad*4 + r;
        out[(size_t)tok*512 + n] = acc[mi][ni][r] + bn;
      }
    }
}

// ---------------- K2: LSH hashing as split-f16 MFMA GEMM + argmax epilogue ----
__global__ __launch_bounds__(256) void k2_mfma(const f16* __restrict__ qkh,
    const f16* __restrict__ qkl, const f16* __restrict__ rotTh, const f16* __restrict__ rotTl,
    unsigned short* __restrict__ bucket, int* __restrict__ hist,
    int* __restrict__ amb_list, int* __restrict__ amb_cnt)
{
  int tid = threadIdx.x;
  int w = tid >> 6, lane = tid & 63;
  int wm = w >> 1, wn = w & 1;
  int c_lane = lane & 15, quad = lane >> 4;
  size_t m0 = (size_t)blockIdx.x*128 + wm*64;

  f16x8 fbh[4][2], fbl[4][2];
  #pragma unroll
  for (int ni=0;ni<4;ni++)
    #pragma unroll
    for (int kb=0;kb<2;kb++){
      int n = wn*64 + ni*16 + c_lane;
      fbh[ni][kb] = *(const f16x8*)&rotTh[n*64 + kb*32 + quad*8];
      fbl[ni][kb] = *(const f16x8*)&rotTl[n*64 + kb*32 + quad*8];
    }

  f32x4 acc[4][4];
  #pragma unroll
  for (int mi=0;mi<4;mi++)
    #pragma unroll
    for (int ni=0;ni<4;ni++) acc[mi][ni] = (f32x4){0.f,0.f,0.f,0.f};

  #pragma unroll
  for (int mi=0;mi<4;mi++){
    size_t row = m0 + mi*16 + c_lane;
    f16x8 fah[2], fal[2];
    #pragma unroll
    for (int kb=0;kb<2;kb++){
      fah[kb] = *(const f16x8*)&qkh[row*64 + kb*32 + quad*8];
      fal[kb] = *(const f16x8*)&qkl[row*64 + kb*32 + quad*8];
    }
    #pragma unroll
    for (int kb=0;kb<2;kb++)
      #pragma unroll
      for (int ni=0;ni<4;ni++){
        acc[mi][ni] = __builtin_amdgcn_mfma_f32_16x16x32_f16(fah[kb], fbh[ni][kb], acc[mi][ni], 0,0,0);
        acc[mi][ni] = __builtin_amdgcn_mfma_f32_16x16x32_f16(fah[kb], fbl[ni][kb], acc[mi][ni], 0,0,0);
        acc[mi][ni] = __builtin_amdgcn_mfma_f32_16x16x32_f16(fal[kb], fbh[ni][kb], acc[mi][ni], 0,0,0);
      }
  }

  #pragma unroll
  for (int mi=0;mi<4;mi++){
    #pragma unroll
    for (int r=0;r<4;r++){
      int tok = (int)m0 + mi*16 + quad*4 + r;
      int bhh = tok >> 12, t = tok & 4095;
      #pragma unroll
      for (int hl=0; hl<2; hl++){
        int h = wn*2 + hl;
        float v0 = acc[mi][2*hl][r];     // col j = c_lane
        float v1 = acc[mi][2*hl+1][r];   // col j = 16 + c_lane
        float m1 = v0, m2 = -1e30f; int b1 = c_lane;
        if (v1 > m1){ m2 = m1; m1 = v1; b1 = 16 + c_lane; } else m2 = v1;
        float n0v = -v0, n1v = -v1;
        if (n0v > m1){ m2 = m1; m1 = n0v; b1 = 32 + c_lane; } else if (n0v > m2) m2 = n0v;
        if (n1v > m1){ m2 = m1; m1 = n1v; b1 = 48 + c_lane; } else if (n1v > m2) m2 = n1v;
        float ssq = v0*v0 + v1*v1;
        #pragma unroll
        for (int d2=1; d2<16; d2<<=1){
          float om1 = __shfl_xor(m1, d2);
          float om2 = __shfl_xor(m2, d2);
          int   ob1 = __shfl_xor(b1, d2);
          ssq += __shfl_xor(ssq, d2);
          if (om1 > m1){ m2 = fmaxf(m1, om2); m1 = om1; b1 = ob1; }
          else         { m2 = fmaxf(m2, om1); }
        }
        if (c_lane == 0){
          float rms = sqrtf(ssq * (1.0f/32.0f));
          if (m1 - m2 < AMB_TAU * rms){
            int idx = atomicAdd(amb_cnt, 1);
            amb_list[idx] = (bhh<<14) | (h<<12) | t;
          } else {
            int g = b1 + (h<<6);
            bucket[((bhh*NHASH + h)<<12) + t] = (unsigned short)g;
            atomicAdd(&hist[bhh*NBUCK + g], 1);
          }
        }
      }
    }
  }
}

// ---------------- K2fix: exact f64 recompute for ambiguous decisions ----------
__global__ __launch_bounds__(64) void k2_fix(const float* __restrict__ qin,
    const float* __restrict__ Wqk, const float* __restrict__ rot,
    const int* __restrict__ amb_list, const int* __restrict__ amb_cnt,
    unsigned short* __restrict__ bucket, int* __restrict__ hist)
{
  __shared__ double qk64[64];
  __shared__ double accs[32];
  int n = *amb_cnt;
  int lane = threadIdx.x;
  for (int it = blockIdx.x; it < n; it += gridDim.x){
    int gid = amb_list[it];
    int t = gid & (T_SZ-1);
    int h = (gid >> 12) & 3;
    int bh = gid >> 14;
    int b = bh >> 3, head = bh & 7;
    const float* qrow = qin + ((size_t)b*T_SZ + t)*DMODEL;
    const float* wcol = Wqk + head*64 + lane;
    double s = 0.0;
    #pragma unroll 8
    for (int d=0; d<512; d++)
      s += (double)qrow[d] * (double)wcol[(size_t)d*512];
    qk64[lane] = s;
    __syncthreads();
    if (lane < 32){
      double a = 0.0;
      #pragma unroll 8
      for (int f=0; f<64; f++)
        a += qk64[f] * (double)rot[f*(NHASH*32) + h*32 + lane];
      accs[lane] = a;
    }
    __syncthreads();
    if (lane == 0){
      double best = accs[0]; int bk = 0;
      for (int k=1;k<64;k++){
        double vv = (k<32)? accs[k] : -accs[k-32];
        if (vv > best){ best = vv; bk = k; }
      }
      int g = bk + (h<<6);
      bucket[((bh*NHASH + h)<<12) + t] = (unsigned short)g;
      atomicAdd(&hist[bh*NBUCK + g], 1);
    }
    __syncthreads();
  }
}

// ---------------- K3: per-bh exclusive prefix over 256 buckets ----------------
__global__ __launch_bounds__(256) void k3_scan(const int* __restrict__ hist, int* __restrict__ starts){
  __shared__ int s[256];
  int bh = blockIdx.x, tid = threadIdx.x;
  int v = hist[bh*256 + tid];
  s[tid] = v; __syncthreads();
  for (int off=1; off<256; off<<=1){
    int a = (tid >= off) ? s[tid-off] : 0;
    __syncthreads();
    s[tid] += a;
    __syncthreads();
  }
  starts[bh*256 + tid] = s[tid] - v;
}

// ---------------- K3b: stable counting-sort scatter ----------------
__global__ __launch_bounds__(64) void k3b_scatter(const unsigned short* __restrict__ bucket,
    const int* __restrict__ starts, int* __restrict__ st)
{
  int blk = blockIdx.x;
  int bh = blk >> 8; int g = blk & 255; int h = g >> 6;
  int lane = threadIdx.x;
  const unsigned short* brow = bucket + ((bh*NHASH + h)<<12);
  int base = starts[bh*NBUCK + g];
  for (int step=0; step<64; step++){
    int t = step*64 + lane;
    bool pred = (brow[t] == (unsigned short)g);
    unsigned long long mask = __ballot(pred);
    if (pred){
      int off = __popcll(mask & ((1ull<<lane) - 1ull));
      st[bh*TOT + base + off] = t;
    }
    base += __popcll(mask);
  }
}

// ---------------- K4: MFMA chunked LSH attention (one wave per (bh,chunk)) ----
__global__ __launch_bounds__(64, 1) void k4_attn(const f16* __restrict__ qk16,
    const f16* __restrict__ v16, const int* __restrict__ st,
    float* __restrict__ lse_out, f16* __restrict__ o_out)
{
  __shared__ __align__(16) char smem[36864];
  f16*   k_lds   = (f16*)smem;
  f16*   p_lds   = (f16*)smem;
  f16*   vT      = (f16*)(smem + 18432);
  float* invnorm = (float*)(smem + 35840);
  int*   kv_t    = (int*)(smem + 36352);

  int blk = blockIdx.x;
  int bh = blk >> 8; int c = blk & 255;
  int h = c >> 6; int cp = (c + 255) & 255;
  int lane = threadIdx.x;
  int c_lane = lane & 15, quad = lane >> 4;
  const int* strow = st + bh*TOT;

  #pragma unroll
  for (int rr=0; rr<2; rr++){
    int row = lane + rr*64;
    int slot = rr ? (cp*64 + lane) : (c*64 + lane);
    int t = strow[slot];
    kv_t[row] = t;
    const f16x8* kr = (const f16x8*)(qk16 + ((size_t)bh*T_SZ + t)*DH);
    const f16x8* vr = (const f16x8*)(v16  + ((size_t)bh*T_SZ + t)*DH);
    f16x8 kv[8], vv[8];
    float ss = 0.f;
    #pragma unroll
    for (int i=0;i<8;i++){
      f16x8 x = kr[i]; kv[i] = x;
      vv[i] = vr[i];
      #pragma unroll
      for (int e=0;e<8;e++){ float f = (float)x[e]; ss += f*f; }
    }
    invnorm[row] = 1.0f / fmaxf(sqrtf(ss), 1e-12f);
    f16x8* kd = (f16x8*)&k_lds[row*KSTRIDE];
    #pragma unroll
    for (int i=0;i<8;i++) kd[i] = kv[i];
    #pragma unroll
    for (int i=0;i<8;i++){
      #pragma unroll
      for (int e=0;e<8;e++) vT[(i*8+e)*PSTRIDE + row] = vv[i][e];
    }
  }

  f16x8 aq[4][2];
  #pragma unroll
  for (int mi=0;mi<4;mi++)
    #pragma unroll
    for (int kb=0;kb<2;kb++)
      aq[mi][kb] = *(const f16x8*)&k_lds[(mi*16 + c_lane)*KSTRIDE + kb*32 + quad*8];

  f32x4 accS[4][8];
  #pragma unroll
  for (int mi=0;mi<4;mi++)
    #pragma unroll
    for (int ni=0;ni<8;ni++)
      accS[mi][ni] = (f32x4){0.f,0.f,0.f,0.f};

  #pragma unroll
  for (int ni=0;ni<8;ni++){
    int rowb = ni*16 + c_lane;
    f16 sc = (f16)invnorm[rowb];
    f16x8 b0 = *(const f16x8*)&k_lds[rowb*KSTRIDE + 0*32 + quad*8];
    f16x8 b1 = *(const f16x8*)&k_lds[rowb*KSTRIDE + 1*32 + quad*8];
    b0 *= sc; b1 *= sc;
    #pragma unroll
    for (int mi=0;mi<4;mi++){
      accS[mi][ni] = __builtin_amdgcn_mfma_f32_16x16x32_f16(aq[mi][0], b0, accS[mi][ni], 0,0,0);
      accS[mi][ni] = __builtin_amdgcn_mfma_f32_16x16x32_f16(aq[mi][1], b1, accS[mi][ni], 0,0,0);
    }
  }

  int tq[4][4];
  #pragma unroll
  for (int mi=0;mi<4;mi++)
    #pragma unroll
    for (int r=0;r<4;r++) tq[mi][r] = kv_t[mi*16 + quad*4 + r];
  int tk[8];
  #pragma unroll
  for (int ni=0;ni<8;ni++) tk[ni] = kv_t[ni*16 + c_lane];

  float mrow[4][4], lrow[4][4];
  #pragma unroll
  for (int mi=0;mi<4;mi++){
    #pragma unroll
    for (int r=0;r<4;r++){
      float mx = -1e30f;
      #pragma unroll
      for (int ni=0;ni<8;ni++){
        float s = accS[mi][ni][r] * 0.125f;
        if (tk[ni] == tq[mi][r]) s = -50000.0f;
        accS[mi][ni][r] = s;
        mx = fmaxf(mx, s);
      }
      mx = fmaxf(mx, __shfl_xor(mx, 1));
      mx = fmaxf(mx, __shfl_xor(mx, 2));
      mx = fmaxf(mx, __shfl_xor(mx, 4));
      mx = fmaxf(mx, __shfl_xor(mx, 8));
      mrow[mi][r] = mx;
      float ls = 0.f;
      #pragma unroll
      for (int ni=0;ni<8;ni++){
        float e = __expf(accS[mi][ni][r] - mx);
        accS[mi][ni][r] = e;
        ls += e;
      }
      ls += __shfl_xor(ls, 1);
      ls += __shfl_xor(ls, 2);
      ls += __shfl_xor(ls, 4);
      ls += __shfl_xor(ls, 8);
      lrow[mi][r] = ls;
    }
  }

  #pragma unroll
  for (int mi=0;mi<4;mi++)
    #pragma unroll
    for (int ni=0;ni<8;ni++)
      #pragma unroll
      for (int r=0;r<4;r++)
        p_lds[(mi*16 + quad*4 + r)*PSTRIDE + ni*16 + c_lane] = (f16)accS[mi][ni][r];

  f16x8 bv[4][4];
  #pragma unroll
  for (int ni2=0;ni2<4;ni2++)
    #pragma unroll
    for (int kb=0;kb<4;kb++)
      bv[ni2][kb] = *(const f16x8*)&vT[(ni2*16 + c_lane)*PSTRIDE + kb*32 + quad*8];

  size_t rowbase = (size_t)(bh*NHASH + h)*T_SZ;
  #pragma unroll
  for (int mi=0;mi<4;mi++){
    f16x8 pa[4];
    #pragma unroll
    for (int kb=0;kb<4;kb++)
      pa[kb] = *(const f16x8*)&p_lds[(mi*16 + c_lane)*PSTRIDE + kb*32 + quad*8];
    f32x4 accO[4];
    #pragma unroll
    for (int ni2=0;ni2<4;ni2++){
      accO[ni2] = (f32x4){0.f,0.f,0.f,0.f};
      #pragma unroll
      for (int kb=0;kb<4;kb++)
        accO[ni2] = __builtin_amdgcn_mfma_f32_16x16x32_f16(pa[kb], bv[ni2][kb], accO[ni2], 0,0,0);
    }
    #pragma unroll
    for (int r=0;r<4;r++){
      int tqi = tq[mi][r];
      float invl = 1.0f / lrow[mi][r];
      f16* orow = o_out + (rowbase + tqi)*DH;
      #pragma unroll
      for (int ni2=0;ni2<4;ni2++)
        orow[ni2*16 + c_lane] = (f16)(accO[ni2][r] * invl);
      if (c_lane == 0)
        lse_out[rowbase + tqi] = mrow[mi][r] + logf(lrow[mi][r]);
    }
  }
}

// ---------------- K5: combine hash rounds -> X_hi/X_lo (f16 split) ----------
__global__ __launch_bounds__(256) void k5_comb(const float* __restrict__ lse,
    const f16* __restrict__ o_f16, f16* __restrict__ Xh, f16* __restrict__ Xl)
{
  int gid = blockIdx.x*256 + threadIdx.x;  // [0, BH*T)
  int t = gid & (T_SZ-1);
  int bh = gid >> 12;
  size_t base = (size_t)bh*NHASH*T_SZ + t;
  float l0 = lse[base];
  float l1 = lse[base + T_SZ];
  float l2 = lse[base + 2*T_SZ];
  float l3 = lse[base + 3*T_SZ];
  float M = fmaxf(fmaxf(l0,l1), fmaxf(l2,l3));
  float e0 = __expf(l0-M), e1 = __expf(l1-M), e2 = __expf(l2-M), e3 = __expf(l3-M);
  float inv = 1.0f/(e0+e1+e2+e3);
  float w0=e0*inv, w1=e1*inv, w2=e2*inv, w3=e3*inv;
  const f16x8* r0 = (const f16x8*)(o_f16 + base*DH);
  const f16x8* r1 = (const f16x8*)(o_f16 + (base + (size_t)T_SZ)*DH);
  const f16x8* r2 = (const f16x8*)(o_f16 + (base + (size_t)2*T_SZ)*DH);
  const f16x8* r3 = (const f16x8*)(o_f16 + (base + (size_t)3*T_SZ)*DH);
  int b = bh >> 3, head = bh & 7;
  size_t xofs = ((size_t)(b*T_SZ + t)*DMODEL + head*DH);
  f16x8* xh = (f16x8*)(Xh + xofs);
  f16x8* xl = (f16x8*)(Xl + xofs);
  #pragma unroll
  for (int i=0; i<8; i++){
    f16x8 a = r0[i], bb = r1[i], cc = r2[i], dd = r3[i];
    f16x8 ho, lo;
    #pragma unroll
    for (int e=0;e<8;e++){
      float res = w0*(float)a[e] + w1*(float)bb[e] + w2*(float)cc[e] + w3*(float)dd[e];
      f16 hh = (f16)res;
      ho[e] = hh; lo[e] = (f16)(res - (float)hh);
    }
    xh[i] = ho; xl[i] = lo;
  }
}

// ---------------- launch ----------------
extern "C" void kernel_launch(void* const* d_in, const int* in_sizes, int n_in,
                              void* d_out, int out_size, void* d_ws, size_t ws_size,
                              hipStream_t stream) {
  const float* queries = (const float*)d_in[0];
  const float* Wqk     = (const float*)d_in[3];
  const float* Wv      = (const float*)d_in[4];
  const float* Wout    = (const float*)d_in[5];
  const float* bout    = (const float*)d_in[6];
  const float* rot     = (const float*)d_in[7];
  float* out = (float*)d_out;

  const size_t SZ_F16  = (size_t)BH*T_SZ*DH*2;        // 16 MB
  const size_t SZ_WT   = (size_t)1536*512*2;          // 1.5 MB
  const size_t SZ_ROT  = (size_t)128*64*2;            // 16 KB
  const size_t SZ_O    = (size_t)BH*NHASH*T_SZ*DH*2;  // 64 MB
  const size_t OFS_X      = 0;
  const size_t OFS_AH     = OFS_X    + 2*SZ_F16;
  const size_t OFS_AL     = OFS_AH   + SZ_F16;
  const size_t OFS_QK16   = OFS_AL   + SZ_F16;
  const size_t OFS_V16    = OFS_QK16 + SZ_F16;
  const size_t OFS_WTH    = OFS_V16  + SZ_F16;
  const size_t OFS_WTL    = OFS_WTH  + SZ_WT;
  const size_t OFS_ROTH   = OFS_WTL  + SZ_WT;
  const size_t OFS_ROTL   = OFS_ROTH + SZ_ROT;
  const size_t OFS_O      = OFS_ROTL + SZ_ROT;
  const size_t OFS_BUCKET = OFS_O    + SZ_O;
  const size_t OFS_HIST   = OFS_BUCKET + (size_t)BH*NHASH*T_SZ*2;
  const size_t OFS_STARTS = OFS_HIST   + (size_t)BH*NBUCK*4;
  const size_t OFS_ST     = OFS_STARTS + (size_t)BH*NBUCK*4;
  const size_t OFS_LSE    = OFS_ST     + (size_t)BH*TOT*4;
  const size_t OFS_AMB    = OFS_LSE    + (size_t)BH*NHASH*T_SZ*4;
  const size_t OFS_CNT    = OFS_AMB    + (size_t)BH*NHASH*T_SZ*4;
  const size_t WS_NEEDED  = OFS_CNT    + 256;
  if (ws_size < WS_NEEDED) return;

  char* ws = (char*)d_ws;
  f16*      qkl    = (f16*)(ws + OFS_X);               // alias with Xh (disjoint lifetime)
  f16*      Xh     = (f16*)(ws + OFS_X);
  f16*      Xl     = (f16*)(ws + OFS_X + SZ_F16);
  f16*      Ah     = (f16*)(ws + OFS_AH);
  f16*      Al     = (f16*)(ws + OFS_AL);
  f16*      qk16   = (f16*)(ws + OFS_QK16);
  f16*      v16    = (f16*)(ws + OFS_V16);
  f16*      Wth    = (f16*)(ws + OFS_WTH);
  f16*      Wtl    = (f16*)(ws + OFS_WTL);
  f16*      rotTh  = (f16*)(ws + OFS_ROTH);
  f16*      rotTl  = (f16*)(ws + OFS_ROTL);
  f16*      o_f16  = (f16*)(ws + OFS_O);
  unsigned short* bucket = (unsigned short*)(ws + OFS_BUCKET);
  int*      hist   = (int*)(ws + OFS_HIST);
  int*      starts = (int*)(ws + OFS_STARTS);
  int*      st     = (int*)(ws + OFS_ST);
  float*    lse    = (float*)(ws + OFS_LSE);
  int*      amb    = (int*)(ws + OFS_AMB);
  int*      cnt    = (int*)(ws + OFS_CNT);

  k0_zero   <<<BH, 256, 0, stream>>>(hist, cnt);
  kw_t      <<<(1536*512)/256, 256, 0, stream>>>(Wqk, Wv, Wout, Wth, Wtl);
  kr_t      <<<(128*64)/256, 256, 0, stream>>>(rot, rotTh, rotTl);
  k1a_split <<<(M_TOK*DMODEL/8)/256, 256, 0, stream>>>(queries, Ah, Al);
  g_qkv     <<<dim3(M_TOK/128, 8), 256, 0, stream>>>(Ah, Al, Wth, Wtl, qk16, qkl, v16);
  k2_mfma   <<<(BH*T_SZ)/128, 256, 0, stream>>>(qk16, qkl, rotTh, rotTl, bucket, hist, amb, cnt);
  k2_fix    <<<2048, 64, 0, stream>>>(queries, Wqk, rot, amb, cnt, bucket, hist);
  k3_scan   <<<BH, 256, 0, stream>>>(hist, starts);
  k3b_scatter<<<BH*NBUCK, 64, 0, stream>>>(bucket, starts, st);
  k4_attn   <<<BH*256, 64, 0, stream>>>(qk16, v16, st, lse, o_f16);
  k5_comb   <<<(BH*T_SZ)/256, 256, 0, stream>>>(lse, o_f16, Xh, Xl);
  g_out     <<<dim3(M_TOK/128, 4), 256, 0, stream>>>(Xh, Xl, Wth, Wtl, bout, out);
}

// Round 8
// 536.716 us; speedup vs baseline: 4.4856x; 1.3513x over previous
//
#include <hip/hip_runtime.h>

typedef unsigned int uint32;
typedef _Float16 f16;
typedef _Float16 f16x8 __attribute__((ext_vector_type(8)));
typedef float f32x4 __attribute__((ext_vector_type(4)));

#define B_SZ 4
#define T_SZ 4096
#define DMODEL 512
#define NHEAD 8
#define DH 64
#define NHASH 4
#define BH (B_SZ*NHEAD)      // 32
#define NBUCK 256
#define TOT (NHASH*T_SZ)     // 16384
#define M_TOK (B_SZ*T_SZ)    // 16384

#define KSTRIDE 72           // f16 elems per LDS row (128B data + 16B pad)
#define PSTRIDE 136

// split-f16 MFMA hash-score worst-case error ~4e-5*rms; keep >=35x margin.
#define AMB_TAU 1.5e-3f

// ---------------- K0: zero histogram + ambiguity counter ----------------
__global__ void k0_zero(int* hist, int* amb_cnt){
  hist[blockIdx.x*256 + threadIdx.x] = 0;
  if (blockIdx.x == 0 && threadIdx.x == 0) *amb_cnt = 0;
}

// ---------------- KW: transpose + split W matrices into Wt[n][k] f16 hi/lo ----
__global__ __launch_bounds__(256) void kw_t(const float* __restrict__ Wqk,
    const float* __restrict__ Wv, const float* __restrict__ Wout,
    f16* __restrict__ Wth, f16* __restrict__ Wtl)
{
  int gid = blockIdx.x*256 + threadIdx.x;   // [0, 1536*512)
  int n = gid >> 9, k = gid & 511;
  int sel = n >> 9, col = n & 511;
  const float* src = (sel==0)? Wqk : (sel==1)? Wv : Wout;
  float v = src[(size_t)k*512 + col];
  f16 h = (f16)v;
  Wth[gid] = h;
  Wtl[gid] = (f16)(v - (float)h);
}

// ---------------- KR: transpose + split rotations into rotT[n=h*32+j][k=dd] --
__global__ __launch_bounds__(256) void kr_t(const float* __restrict__ rot,
    f16* __restrict__ rotTh, f16* __restrict__ rotTl)
{
  int gid = blockIdx.x*256 + threadIdx.x;   // [0, 128*64)
  int n = gid >> 6, dd = gid & 63;
  float v = rot[dd*128 + n];
  f16 h = (f16)v;
  rotTh[gid] = h;
  rotTl[gid] = (f16)(v - (float)h);
}

// ---------------- K1a: split queries (f32) -> A_hi/A_lo (f16) ----------------
__global__ __launch_bounds__(256) void k1a_split(const float* __restrict__ qin,
    f16* __restrict__ Ah, f16* __restrict__ Al)
{
  size_t gid = (size_t)blockIdx.x*256 + threadIdx.x;   // handles 8 floats
  const float4* src = (const float4*)(qin) + gid*2;
  float4 x0 = src[0], x1 = src[1];
  float v[8] = {x0.x,x0.y,x0.z,x0.w, x1.x,x1.y,x1.z,x1.w};
  f16x8 h, l;
  #pragma unroll
  for (int e=0;e<8;e++){ f16 hh=(f16)v[e]; h[e]=hh; l[e]=(f16)(v[e]-(float)hh); }
  ((f16x8*)Ah)[gid] = h;
  ((f16x8*)Al)[gid] = l;
}

// ---------------- G1: split-f16 MFMA GEMM  qk|v = queries @ [Wqk|Wv] ---------
__global__ __launch_bounds__(256) void g_qkv(const f16* __restrict__ Ah,
    const f16* __restrict__ Al, const f16* __restrict__ Wth, const f16* __restrict__ Wtl,
    f16* __restrict__ qk16, f16* __restrict__ qkl, f16* __restrict__ v16)
{
  __shared__ f16 ah[128*KSTRIDE], al[128*KSTRIDE], bh[128*KSTRIDE], bl[128*KSTRIDE];
  int tid = threadIdx.x;
  int m0 = blockIdx.x*128, n0 = blockIdx.y*128;
  int w = tid >> 6, lane = tid & 63;
  int wm = w >> 1, wn = w & 1;
  int c_lane = lane & 15, quad = lane >> 4;

  f32x4 acc[4][4];
  #pragma unroll
  for (int mi=0;mi<4;mi++)
    #pragma unroll
    for (int ni=0;ni<4;ni++) acc[mi][ni] = (f32x4){0.f,0.f,0.f,0.f};

  int sr = tid >> 1, sc = (tid & 1) * 32;
  for (int kc=0; kc<8; kc++){
    int k0 = kc*64;
    {
      const f16x8* pah = (const f16x8*)(Ah + (size_t)(m0+sr)*512 + k0 + sc);
      const f16x8* pal = (const f16x8*)(Al + (size_t)(m0+sr)*512 + k0 + sc);
      const f16x8* pbh = (const f16x8*)(Wth + (size_t)(n0+sr)*512 + k0 + sc);
      const f16x8* pbl = (const f16x8*)(Wtl + (size_t)(n0+sr)*512 + k0 + sc);
      f16x8* dah = (f16x8*)&ah[sr*KSTRIDE + sc];
      f16x8* dal = (f16x8*)&al[sr*KSTRIDE + sc];
      f16x8* dbh = (f16x8*)&bh[sr*KSTRIDE + sc];
      f16x8* dbl = (f16x8*)&bl[sr*KSTRIDE + sc];
      #pragma unroll
      for (int i=0;i<4;i++){ dah[i]=pah[i]; dal[i]=pal[i]; dbh[i]=pbh[i]; dbl[i]=pbl[i]; }
    }
    __syncthreads();
    f16x8 fah[4][2], fal[4][2], fbh[4][2], fbl[4][2];
    #pragma unroll
    for (int i=0;i<4;i++)
      #pragma unroll
      for (int kb=0;kb<2;kb++){
        int ma = (wm*64 + i*16 + c_lane)*KSTRIDE + kb*32 + quad*8;
        int nb = (wn*64 + i*16 + c_lane)*KSTRIDE + kb*32 + quad*8;
        fah[i][kb] = *(const f16x8*)&ah[ma];
        fal[i][kb] = *(const f16x8*)&al[ma];
        fbh[i][kb] = *(const f16x8*)&bh[nb];
        fbl[i][kb] = *(const f16x8*)&bl[nb];
      }
    #pragma unroll
    for (int kb=0;kb<2;kb++)
      #pragma unroll
      for (int p=0;p<3;p++)
        #pragma unroll
        for (int mi=0;mi<4;mi++)
          #pragma unroll
          for (int ni=0;ni<4;ni++){
            f16x8 a = (p==2)? fal[mi][kb] : fah[mi][kb];
            f16x8 b = (p==1)? fbl[ni][kb] : fbh[ni][kb];
            acc[mi][ni] = __builtin_amdgcn_mfma_f32_16x16x32_f16(a, b, acc[mi][ni], 0,0,0);
          }
    __syncthreads();
  }

  // epilogue: n<512 -> qk16(hi)+qkl(lo); n>=512 -> v16
  #pragma unroll
  for (int mi=0;mi<4;mi++)
    #pragma unroll
    for (int ni=0;ni<4;ni++)
      #pragma unroll
      for (int r=0;r<4;r++){
        int n = n0 + wn*64 + ni*16 + c_lane;
        int tok = m0 + wm*64 + mi*16 + quad*4 + r;
        float val = acc[mi][ni][r];
        int b = tok >> 12, tp = tok & 4095;
        if (n < 512){
          int head = n >> 6, dd = n & 63;
          size_t idx = ((size_t)(b*NHEAD+head)*T_SZ + tp)*DH + dd;
          f16 hv = (f16)val;
          qk16[idx] = hv;
          qkl[idx]  = (f16)(val - (float)hv);
        } else {
          int j = n - 512, head = j >> 6, dd = j & 63;
          size_t idx = ((size_t)(b*NHEAD+head)*T_SZ + tp)*DH + dd;
          v16[idx] = (f16)val;
        }
      }
}

// ---------------- G2: split-f16 MFMA GEMM  out = X @ Wout + bias -------------
__global__ __launch_bounds__(256) void g_out(const f16* __restrict__ Xh,
    const f16* __restrict__ Xl, const f16* __restrict__ Wth, const f16* __restrict__ Wtl,
    const float* __restrict__ bout, float* __restrict__ out)
{
  __shared__ f16 ah[128*KSTRIDE], al[128*KSTRIDE], bh[128*KSTRIDE], bl[128*KSTRIDE];
  int tid = threadIdx.x;
  int m0 = blockIdx.x*128, n0 = blockIdx.y*128;
  int w = tid >> 6, lane = tid & 63;
  int wm = w >> 1, wn = w & 1;
  int c_lane = lane & 15, quad = lane >> 4;
  const f16* Bh_base = Wth + (size_t)1024*512;   // Wout section
  const f16* Bl_base = Wtl + (size_t)1024*512;

  f32x4 acc[4][4];
  #pragma unroll
  for (int mi=0;mi<4;mi++)
    #pragma unroll
    for (int ni=0;ni<4;ni++) acc[mi][ni] = (f32x4){0.f,0.f,0.f,0.f};

  int sr = tid >> 1, sc = (tid & 1) * 32;
  for (int kc=0; kc<8; kc++){
    int k0 = kc*64;
    {
      const f16x8* pah = (const f16x8*)(Xh + (size_t)(m0+sr)*512 + k0 + sc);
      const f16x8* pal = (const f16x8*)(Xl + (size_t)(m0+sr)*512 + k0 + sc);
      const f16x8* pbh = (const f16x8*)(Bh_base + (size_t)(n0+sr)*512 + k0 + sc);
      const f16x8* pbl = (const f16x8*)(Bl_base + (size_t)(n0+sr)*512 + k0 + sc);
      f16x8* dah = (f16x8*)&ah[sr*KSTRIDE + sc];
      f16x8* dal = (f16x8*)&al[sr*KSTRIDE + sc];
      f16x8* dbh = (f16x8*)&bh[sr*KSTRIDE + sc];
      f16x8* dbl = (f16x8*)&bl[sr*KSTRIDE + sc];
      #pragma unroll
      for (int i=0;i<4;i++){ dah[i]=pah[i]; dal[i]=pal[i]; dbh[i]=pbh[i]; dbl[i]=pbl[i]; }
    }
    __syncthreads();
    f16x8 fah[4][2], fal[4][2], fbh[4][2], fbl[4][2];
    #pragma unroll
    for (int i=0;i<4;i++)
      #pragma unroll
      for (int kb=0;kb<2;kb++){
        int ma = (wm*64 + i*16 + c_lane)*KSTRIDE + kb*32 + quad*8;
        int nb = (wn*64 + i*16 + c_lane)*KSTRIDE + kb*32 + quad*8;
        fah[i][kb] = *(const f16x8*)&ah[ma];
        fal[i][kb] = *(const f16x8*)&al[ma];
        fbh[i][kb] = *(const f16x8*)&bh[nb];
        fbl[i][kb] = *(const f16x8*)&bl[nb];
      }
    #pragma unroll
    for (int kb=0;kb<2;kb++)
      #pragma unroll
      for (int p=0;p<3;p++)
        #pragma unroll
        for (int mi=0;mi<4;mi++)
          #pragma unroll
          for (int ni=0;ni<4;ni++){
            f16x8 a = (p==2)? fal[mi][kb] : fah[mi][kb];
            f16x8 b = (p==1)? fbl[ni][kb] : fbh[ni][kb];
            acc[mi][ni] = __builtin_amdgcn_mfma_f32_16x16x32_f16(a, b, acc[mi][ni], 0,0,0);
          }
    __syncthreads();
  }

  #pragma unroll
  for (int mi=0;mi<4;mi++)
    #pragma unroll
    for (int ni=0;ni<4;ni++){
      int n = n0 + wn*64 + ni*16 + c_lane;
      float bn = bout[n];
      #pragma unroll
      for (int r=0;r<4;r++){
        int tok = m0 + wm*64 + mi*16 + quad*4 + r;
        out[(size_t)tok*512 + n] = acc[mi][ni][r] + bn;
      }
    }
}

// ---------------- K2: LSH hashing as split-f16 MFMA GEMM + argmax epilogue ----
__global__ __launch_bounds__(256) void k2_mfma(const f16* __restrict__ qkh,
    const f16* __restrict__ qkl, const f16* __restrict__ rotTh, const f16* __restrict__ rotTl,
    unsigned short* __restrict__ bucket, int* __restrict__ hist,
    int* __restrict__ amb_list, int* __restrict__ amb_cnt)
{
  int tid = threadIdx.x;
  int w = tid >> 6, lane = tid & 63;
  int wm = w >> 1, wn = w & 1;
  int c_lane = lane & 15, quad = lane >> 4;
  size_t m0 = (size_t)blockIdx.x*128 + wm*64;

  f16x8 fbh[4][2], fbl[4][2];
  #pragma unroll
  for (int ni=0;ni<4;ni++)
    #pragma unroll
    for (int kb=0;kb<2;kb++){
      int n = wn*64 + ni*16 + c_lane;
      fbh[ni][kb] = *(const f16x8*)&rotTh[n*64 + kb*32 + quad*8];
      fbl[ni][kb] = *(const f16x8*)&rotTl[n*64 + kb*32 + quad*8];
    }

  f32x4 acc[4][4];
  #pragma unroll
  for (int mi=0;mi<4;mi++)
    #pragma unroll
    for (int ni=0;ni<4;ni++) acc[mi][ni] = (f32x4){0.f,0.f,0.f,0.f};

  #pragma unroll
  for (int mi=0;mi<4;mi++){
    size_t row = m0 + mi*16 + c_lane;
    f16x8 fah[2], fal[2];
    #pragma unroll
    for (int kb=0;kb<2;kb++){
      fah[kb] = *(const f16x8*)&qkh[row*64 + kb*32 + quad*8];
      fal[kb] = *(const f16x8*)&qkl[row*64 + kb*32 + quad*8];
    }
    #pragma unroll
    for (int kb=0;kb<2;kb++)
      #pragma unroll
      for (int ni=0;ni<4;ni++){
        acc[mi][ni] = __builtin_amdgcn_mfma_f32_16x16x32_f16(fah[kb], fbh[ni][kb], acc[mi][ni], 0,0,0);
        acc[mi][ni] = __builtin_amdgcn_mfma_f32_16x16x32_f16(fah[kb], fbl[ni][kb], acc[mi][ni], 0,0,0);
        acc[mi][ni] = __builtin_amdgcn_mfma_f32_16x16x32_f16(fal[kb], fbh[ni][kb], acc[mi][ni], 0,0,0);
      }
  }

  #pragma unroll
  for (int mi=0;mi<4;mi++){
    #pragma unroll
    for (int r=0;r<4;r++){
      int tok = (int)m0 + mi*16 + quad*4 + r;
      int bhh = tok >> 12, t = tok & 4095;
      #pragma unroll
      for (int hl=0; hl<2; hl++){
        int h = wn*2 + hl;
        float v0 = acc[mi][2*hl][r];     // col j = c_lane
        float v1 = acc[mi][2*hl+1][r];   // col j = 16 + c_lane
        float m1 = v0, m2 = -1e30f; int b1 = c_lane;
        if (v1 > m1){ m2 = m1; m1 = v1; b1 = 16 + c_lane; } else m2 = v1;
        float n0v = -v0, n1v = -v1;
        if (n0v > m1){ m2 = m1; m1 = n0v; b1 = 32 + c_lane; } else if (n0v > m2) m2 = n0v;
        if (n1v > m1){ m2 = m1; m1 = n1v; b1 = 48 + c_lane; } else if (n1v > m2) m2 = n1v;
        float ssq = v0*v0 + v1*v1;
        #pragma unroll
        for (int d2=1; d2<16; d2<<=1){
          float om1 = __shfl_xor(m1, d2);
          float om2 = __shfl_xor(m2, d2);
          int   ob1 = __shfl_xor(b1, d2);
          ssq += __shfl_xor(ssq, d2);
          if (om1 > m1){ m2 = fmaxf(m1, om2); m1 = om1; b1 = ob1; }
          else         { m2 = fmaxf(m2, om1); }
        }
        if (c_lane == 0){
          float rms = sqrtf(ssq * (1.0f/32.0f));
          if (m1 - m2 < AMB_TAU * rms){
            int idx = atomicAdd(amb_cnt, 1);
            amb_list[idx] = (bhh<<14) | (h<<12) | t;
          } else {
            int g = b1 + (h<<6);
            bucket[((bhh*NHASH + h)<<12) + t] = (unsigned short)g;
            atomicAdd(&hist[bhh*NBUCK + g], 1);
          }
        }
      }
    }
  }
}

// ---------------- K2fix: exact f64 recompute for ambiguous decisions ----------
// qrow staged coalesced into LDS; lane=j does 256B/iter coalesced Wqk reads.
// f64 accumulation order identical to the original sequential d=0..511 loop.
__global__ __launch_bounds__(64) void k2_fix(const float* __restrict__ qin,
    const float* __restrict__ Wqk, const float* __restrict__ rot,
    const int* __restrict__ amb_list, const int* __restrict__ amb_cnt,
    unsigned short* __restrict__ bucket, int* __restrict__ hist)
{
  __shared__ __align__(16) float qs[512];
  __shared__ double qk64[64];
  __shared__ double accs[32];
  int n = *amb_cnt;
  int lane = threadIdx.x;
  for (int it = blockIdx.x; it < n; it += gridDim.x){
    int gid = amb_list[it];
    int t = gid & (T_SZ-1);
    int h = (gid >> 12) & 3;
    int bh = gid >> 14;
    int b = bh >> 3, head = bh & 7;
    // stage qrow (2 KB) coalesced
    const float4* qrow4 = (const float4*)(qin + ((size_t)b*T_SZ + t)*DMODEL);
    float4 x0 = qrow4[lane];
    float4 x1 = qrow4[lane + 64];
    *(float4*)&qs[lane*4]       = x0;
    *(float4*)&qs[256 + lane*4] = x1;
    __syncthreads();
    // lane = output dim j: sequential f64 over d, coalesced Wqk reads
    const float* wcol = Wqk + head*64 + lane;
    double s = 0.0;
    #pragma unroll 16
    for (int d=0; d<512; d++)
      s += (double)qs[d] * (double)wcol[(size_t)d*512];
    qk64[lane] = s;
    __syncthreads();
    if (lane < 32){
      double a = 0.0;
      #pragma unroll 16
      for (int f=0; f<64; f++)
        a += qk64[f] * (double)rot[f*(NHASH*32) + h*32 + lane];
      accs[lane] = a;
    }
    __syncthreads();
    if (lane == 0){
      double best = accs[0]; int bk = 0;
      for (int k=1;k<64;k++){
        double vv = (k<32)? accs[k] : -accs[k-32];
        if (vv > best){ best = vv; bk = k; }
      }
      int g = bk + (h<<6);
      bucket[((bh*NHASH + h)<<12) + t] = (unsigned short)g;
      atomicAdd(&hist[bh*NBUCK + g], 1);
    }
    __syncthreads();
  }
}

// ---------------- K3: per-bh exclusive prefix over 256 buckets ----------------
__global__ __launch_bounds__(256) void k3_scan(const int* __restrict__ hist, int* __restrict__ starts){
  __shared__ int s[256];
  int bh = blockIdx.x, tid = threadIdx.x;
  int v = hist[bh*256 + tid];
  s[tid] = v; __syncthreads();
  for (int off=1; off<256; off<<=1){
    int a = (tid >= off) ? s[tid-off] : 0;
    __syncthreads();
    s[tid] += a;
    __syncthreads();
  }
  starts[bh*256 + tid] = s[tid] - v;
}

// ---------------- K3b: stable counting-sort scatter ----------------
__global__ __launch_bounds__(64) void k3b_scatter(const unsigned short* __restrict__ bucket,
    const int* __restrict__ starts, int* __restrict__ st)
{
  int blk = blockIdx.x;
  int bh = blk >> 8; int g = blk & 255; int h = g >> 6;
  int lane = threadIdx.x;
  const unsigned short* brow = bucket + ((bh*NHASH + h)<<12);
  int base = starts[bh*NBUCK + g];
  for (int step=0; step<64; step++){
    int t = step*64 + lane;
    bool pred = (brow[t] == (unsigned short)g);
    unsigned long long mask = __ballot(pred);
    if (pred){
      int off = __popcll(mask & ((1ull<<lane) - 1ull));
      st[bh*TOT + base + off] = t;
    }
    base += __popcll(mask);
  }
}

// ---------------- K4: MFMA chunked LSH attention (one wave per (bh,chunk)) ----
__global__ __launch_bounds__(64, 1) void k4_attn(const f16* __restrict__ qk16,
    const f16* __restrict__ v16, const int* __restrict__ st,
    float* __restrict__ lse_out, f16* __restrict__ o_out)
{
  __shared__ __align__(16) char smem[36864];
  f16*   k_lds   = (f16*)smem;
  f16*   p_lds   = (f16*)smem;
  f16*   vT      = (f16*)(smem + 18432);
  float* invnorm = (float*)(smem + 35840);
  int*   kv_t    = (int*)(smem + 36352);

  int blk = blockIdx.x;
  int bh = blk >> 8; int c = blk & 255;
  int h = c >> 6; int cp = (c + 255) & 255;
  int lane = threadIdx.x;
  int c_lane = lane & 15, quad = lane >> 4;
  const int* strow = st + bh*TOT;

  #pragma unroll
  for (int rr=0; rr<2; rr++){
    int row = lane + rr*64;
    int slot = rr ? (cp*64 + lane) : (c*64 + lane);
    int t = strow[slot];
    kv_t[row] = t;
    const f16x8* kr = (const f16x8*)(qk16 + ((size_t)bh*T_SZ + t)*DH);
    const f16x8* vr = (const f16x8*)(v16  + ((size_t)bh*T_SZ + t)*DH);
    f16x8 kv[8], vv[8];
    float ss = 0.f;
    #pragma unroll
    for (int i=0;i<8;i++){
      f16x8 x = kr[i]; kv[i] = x;
      vv[i] = vr[i];
      #pragma unroll
      for (int e=0;e<8;e++){ float f = (float)x[e]; ss += f*f; }
    }
    invnorm[row] = 1.0f / fmaxf(sqrtf(ss), 1e-12f);
    f16x8* kd = (f16x8*)&k_lds[row*KSTRIDE];
    #pragma unroll
    for (int i=0;i<8;i++) kd[i] = kv[i];
    #pragma unroll
    for (int i=0;i<8;i++){
      #pragma unroll
      for (int e=0;e<8;e++) vT[(i*8+e)*PSTRIDE + row] = vv[i][e];
    }
  }

  f16x8 aq[4][2];
  #pragma unroll
  for (int mi=0;mi<4;mi++)
    #pragma unroll
    for (int kb=0;kb<2;kb++)
      aq[mi][kb] = *(const f16x8*)&k_lds[(mi*16 + c_lane)*KSTRIDE + kb*32 + quad*8];

  f32x4 accS[4][8];
  #pragma unroll
  for (int mi=0;mi<4;mi++)
    #pragma unroll
    for (int ni=0;ni<8;ni++)
      accS[mi][ni] = (f32x4){0.f,0.f,0.f,0.f};

  #pragma unroll
  for (int ni=0;ni<8;ni++){
    int rowb = ni*16 + c_lane;
    f16 sc = (f16)invnorm[rowb];
    f16x8 b0 = *(const f16x8*)&k_lds[rowb*KSTRIDE + 0*32 + quad*8];
    f16x8 b1 = *(const f16x8*)&k_lds[rowb*KSTRIDE + 1*32 + quad*8];
    b0 *= sc; b1 *= sc;
    #pragma unroll
    for (int mi=0;mi<4;mi++){
      accS[mi][ni] = __builtin_amdgcn_mfma_f32_16x16x32_f16(aq[mi][0], b0, accS[mi][ni], 0,0,0);
      accS[mi][ni] = __builtin_amdgcn_mfma_f32_16x16x32_f16(aq[mi][1], b1, accS[mi][ni], 0,0,0);
    }
  }

  int tq[4][4];
  #pragma unroll
  for (int mi=0;mi<4;mi++)
    #pragma unroll
    for (int r=0;r<4;r++) tq[mi][r] = kv_t[mi*16 + quad*4 + r];
  int tk[8];
  #pragma unroll
  for (int ni=0;ni<8;ni++) tk[ni] = kv_t[ni*16 + c_lane];

  float mrow[4][4], lrow[4][4];
  #pragma unroll
  for (int mi=0;mi<4;mi++){
    #pragma unroll
    for (int r=0;r<4;r++){
      float mx = -1e30f;
      #pragma unroll
      for (int ni=0;ni<8;ni++){
        float s = accS[mi][ni][r] * 0.125f;
        if (tk[ni] == tq[mi][r]) s = -50000.0f;
        accS[mi][ni][r] = s;
        mx = fmaxf(mx, s);
      }
      mx = fmaxf(mx, __shfl_xor(mx, 1));
      mx = fmaxf(mx, __shfl_xor(mx, 2));
      mx = fmaxf(mx, __shfl_xor(mx, 4));
      mx = fmaxf(mx, __shfl_xor(mx, 8));
      mrow[mi][r] = mx;
      float ls = 0.f;
      #pragma unroll
      for (int ni=0;ni<8;ni++){
        float e = __expf(accS[mi][ni][r] - mx);
        accS[mi][ni][r] = e;
        ls += e;
      }
      ls += __shfl_xor(ls, 1);
      ls += __shfl_xor(ls, 2);
      ls += __shfl_xor(ls, 4);
      ls += __shfl_xor(ls, 8);
      lrow[mi][r] = ls;
    }
  }

  #pragma unroll
  for (int mi=0;mi<4;mi++)
    #pragma unroll
    for (int ni=0;ni<8;ni++)
      #pragma unroll
      for (int r=0;r<4;r++)
        p_lds[(mi*16 + quad*4 + r)*PSTRIDE + ni*16 + c_lane] = (f16)accS[mi][ni][r];

  f16x8 bv[4][4];
  #pragma unroll
  for (int ni2=0;ni2<4;ni2++)
    #pragma unroll
    for (int kb=0;kb<4;kb++)
      bv[ni2][kb] = *(const f16x8*)&vT[(ni2*16 + c_lane)*PSTRIDE + kb*32 + quad*8];

  size_t rowbase = (size_t)(bh*NHASH + h)*T_SZ;
  #pragma unroll
  for (int mi=0;mi<4;mi++){
    f16x8 pa[4];
    #pragma unroll
    for (int kb=0;kb<4;kb++)
      pa[kb] = *(const f16x8*)&p_lds[(mi*16 + c_lane)*PSTRIDE + kb*32 + quad*8];
    f32x4 accO[4];
    #pragma unroll
    for (int ni2=0;ni2<4;ni2++){
      accO[ni2] = (f32x4){0.f,0.f,0.f,0.f};
      #pragma unroll
      for (int kb=0;kb<4;kb++)
        accO[ni2] = __builtin_amdgcn_mfma_f32_16x16x32_f16(pa[kb], bv[ni2][kb], accO[ni2], 0,0,0);
    }
    #pragma unroll
    for (int r=0;r<4;r++){
      int tqi = tq[mi][r];
      float invl = 1.0f / lrow[mi][r];
      f16* orow = o_out + (rowbase + tqi)*DH;
      #pragma unroll
      for (int ni2=0;ni2<4;ni2++)
        orow[ni2*16 + c_lane] = (f16)(accO[ni2][r] * invl);
      if (c_lane == 0)
        lse_out[rowbase + tqi] = mrow[mi][r] + logf(lrow[mi][r]);
    }
  }
}

// ---------------- K5: combine hash rounds -> X_hi/X_lo (f16 split) ----------
__global__ __launch_bounds__(256) void k5_comb(const float* __restrict__ lse,
    const f16* __restrict__ o_f16, f16* __restrict__ Xh, f16* __restrict__ Xl)
{
  int gid = blockIdx.x*256 + threadIdx.x;  // [0, BH*T)
  int t = gid & (T_SZ-1);
  int bh = gid >> 12;
  size_t base = (size_t)bh*NHASH*T_SZ + t;
  float l0 = lse[base];
  float l1 = lse[base + T_SZ];
  float l2 = lse[base + 2*T_SZ];
  float l3 = lse[base + 3*T_SZ];
  float M = fmaxf(fmaxf(l0,l1), fmaxf(l2,l3));
  float e0 = __expf(l0-M), e1 = __expf(l1-M), e2 = __expf(l2-M), e3 = __expf(l3-M);
  float inv = 1.0f/(e0+e1+e2+e3);
  float w0=e0*inv, w1=e1*inv, w2=e2*inv, w3=e3*inv;
  const f16x8* r0 = (const f16x8*)(o_f16 + base*DH);
  const f16x8* r1 = (const f16x8*)(o_f16 + (base + (size_t)T_SZ)*DH);
  const f16x8* r2 = (const f16x8*)(o_f16 + (base + (size_t)2*T_SZ)*DH);
  const f16x8* r3 = (const f16x8*)(o_f16 + (base + (size_t)3*T_SZ)*DH);
  int b = bh >> 3, head = bh & 7;
  size_t xofs = ((size_t)(b*T_SZ + t)*DMODEL + head*DH);
  f16x8* xh = (f16x8*)(Xh + xofs);
  f16x8* xl = (f16x8*)(Xl + xofs);
  #pragma unroll
  for (int i=0; i<8; i++){
    f16x8 a = r0[i], bb = r1[i], cc = r2[i], dd = r3[i];
    f16x8 ho, lo;
    #pragma unroll
    for (int e=0;e<8;e++){
      float res = w0*(float)a[e] + w1*(float)bb[e] + w2*(float)cc[e] + w3*(float)dd[e];
      f16 hh = (f16)res;
      ho[e] = hh; lo[e] = (f16)(res - (float)hh);
    }
    xh[i] = ho; xl[i] = lo;
  }
}

// ---------------- launch ----------------
extern "C" void kernel_launch(void* const* d_in, const int* in_sizes, int n_in,
                              void* d_out, int out_size, void* d_ws, size_t ws_size,
                              hipStream_t stream) {
  const float* queries = (const float*)d_in[0];
  const float* Wqk     = (const float*)d_in[3];
  const float* Wv      = (const float*)d_in[4];
  const float* Wout    = (const float*)d_in[5];
  const float* bout    = (const float*)d_in[6];
  const float* rot     = (const float*)d_in[7];
  float* out = (float*)d_out;

  const size_t SZ_F16  = (size_t)BH*T_SZ*DH*2;        // 16 MB
  const size_t SZ_WT   = (size_t)1536*512*2;          // 1.5 MB
  const size_t SZ_ROT  = (size_t)128*64*2;            // 16 KB
  const size_t SZ_O    = (size_t)BH*NHASH*T_SZ*DH*2;  // 64 MB
  const size_t OFS_X      = 0;
  const size_t OFS_AH     = OFS_X    + 2*SZ_F16;
  const size_t OFS_AL     = OFS_AH   + SZ_F16;
  const size_t OFS_QK16   = OFS_AL   + SZ_F16;
  const size_t OFS_V16    = OFS_QK16 + SZ_F16;
  const size_t OFS_WTH    = OFS_V16  + SZ_F16;
  const size_t OFS_WTL    = OFS_WTH  + SZ_WT;
  const size_t OFS_ROTH   = OFS_WTL  + SZ_WT;
  const size_t OFS_ROTL   = OFS_ROTH + SZ_ROT;
  const size_t OFS_O      = OFS_ROTL + SZ_ROT;
  const size_t OFS_BUCKET = OFS_O    + SZ_O;
  const size_t OFS_HIST   = OFS_BUCKET + (size_t)BH*NHASH*T_SZ*2;
  const size_t OFS_STARTS = OFS_HIST   + (size_t)BH*NBUCK*4;
  const size_t OFS_ST     = OFS_STARTS + (size_t)BH*NBUCK*4;
  const size_t OFS_LSE    = OFS_ST     + (size_t)BH*TOT*4;
  const size_t OFS_AMB    = OFS_LSE    + (size_t)BH*NHASH*T_SZ*4;
  const size_t OFS_CNT    = OFS_AMB    + (size_t)BH*NHASH*T_SZ*4;
  const size_t WS_NEEDED  = OFS_CNT    + 256;
  if (ws_size < WS_NEEDED) return;

  char* ws = (char*)d_ws;
  f16*      qkl    = (f16*)(ws + OFS_X);               // alias with Xh (disjoint lifetime)
  f16*      Xh     = (f16*)(ws + OFS_X);
  f16*      Xl     = (f16*)(ws + OFS_X + SZ_F16);
  f16*      Ah     = (f16*)(ws + OFS_AH);
  f16*      Al     = (f16*)(ws + OFS_AL);
  f16*      qk16   = (f16*)(ws + OFS_QK16);
  f16*      v16    = (f16*)(ws + OFS_V16);
  f16*      Wth    = (f16*)(ws + OFS_WTH);
  f16*      Wtl    = (f16*)(ws + OFS_WTL);
  f16*      rotTh  = (f16*)(ws + OFS_ROTH);
  f16*      rotTl  = (f16*)(ws + OFS_ROTL);
  f16*      o_f16  = (f16*)(ws + OFS_O);
  unsigned short* bucket = (unsigned short*)(ws + OFS_BUCKET);
  int*      hist   = (int*)(ws + OFS_HIST);
  int*      starts = (int*)(ws + OFS_STARTS);
  int*      st     = (int*)(ws + OFS_ST);
  float*    lse    = (float*)(ws + OFS_LSE);
  int*      amb    = (int*)(ws + OFS_AMB);
  int*      cnt    = (int*)(ws + OFS_CNT);

  k0_zero   <<<BH, 256, 0, stream>>>(hist, cnt);
  kw_t      <<<(1536*512)/256, 256, 0, stream>>>(Wqk, Wv, Wout, Wth, Wtl);
  kr_t      <<<(128*64)/256, 256, 0, stream>>>(rot, rotTh, rotTl);
  k1a_split <<<(M_TOK*DMODEL/8)/256, 256, 0, stream>>>(queries, Ah, Al);
  g_qkv     <<<dim3(M_TOK/128, 8), 256, 0, stream>>>(Ah, Al, Wth, Wtl, qk16, qkl, v16);
  k2_mfma   <<<(BH*T_SZ)/128, 256, 0, stream>>>(qk16, qkl, rotTh, rotTl, bucket, hist, amb, cnt);
  k2_fix    <<<2048, 64, 0, stream>>>(queries, Wqk, rot, amb, cnt, bucket, hist);
  k3_scan   <<<BH, 256, 0, stream>>>(hist, starts);
  k3b_scatter<<<BH*NBUCK, 64, 0, stream>>>(bucket, starts, st);
  k4_attn   <<<BH*256, 64, 0, stream>>>(qk16, v16, st, lse, o_f16);
  k5_comb   <<<(BH*T_SZ)/256, 256, 0, stream>>>(lse, o_f16, Xh, Xl);
  g_out     <<<dim3(M_TOK/128, 4), 256, 0, stream>>>(Xh, Xl, Wth, Wtl, bout, out);
}